// Round 19
// baseline (656.280 us; speedup 1.0000x reference)
//
#include <hip/hip_runtime.h>

typedef __attribute__((ext_vector_type(4))) float f32x4;
typedef __attribute__((ext_vector_type(2))) unsigned int u32x2;
typedef _Float16 f16x8 __attribute__((ext_vector_type(8)));
typedef _Float16 h2    __attribute__((ext_vector_type(2)));

#define TTOK 10000
#define SBAR() __builtin_amdgcn_sched_barrier(0)

__device__ __forceinline__ h2 pkh(float lo, float hi){
  auto t = __builtin_amdgcn_cvt_pkrtz(lo, hi);   // __fp16 x2 -> bitcast to h2
  union{ decltype(t) a; h2 b; } c; c.a = t; return c.b;
}
__device__ __forceinline__ unsigned h2u(h2 v){ union{h2 h; unsigned u;} c; c.h=v; return c.u; }

__device__ __forceinline__ unsigned short f2h(float f){
  _Float16 h = (_Float16)f;                 // RNE
  union{_Float16 h; unsigned short u;} c; c.h = h; return c.u;
}

// ---------------- prep: fragment-linear f16 weights, hb+t*tw seeds, c ----------------
// wb[((jj*4+kc)*64 + l)*8 + i] = W[jj*16+q][kc*32+g*8+i], l=g*16+q: a wave's
// 16B/lane fragment read is 64 lanes x contiguous = 1024B (conflict-free),
// address = base + immediate (round 13, verified).
__global__ void cnf_prep(const float* __restrict__ h, const float* __restrict__ Wx,
                         const float* __restrict__ wxt, const float* __restrict__ bx,
                         const float* __restrict__ Wh, const float* __restrict__ wht,
                         const float* __restrict__ bh, const float* __restrict__ W2,
                         float* __restrict__ hbt, float* __restrict__ cv,
                         unsigned short* __restrict__ wxb, unsigned short* __restrict__ w2b)
{
  const int b = blockIdx.x, t = threadIdx.x;
  if (b < 16) {
    const int jj = b & 7;
    const float* W = (b < 8) ? Wx : W2;
    unsigned short* dst = (b < 8) ? wxb : w2b;
    const int kc = t>>6, l = t&63, q = l&15, g = l>>4;
    #pragma unroll
    for (int i=0;i<8;++i)
      dst[((jj*4+kc)*64 + l)*8 + i] = f2h(W[(jj*16+q)*128 + kc*32 + g*8 + i]);
  } else if (b < 18) {
    for (int i=0;i<4;++i){
      int idx = i*256 + t;
      int sb = (b-16)*8 + (idx>>7);
      int j  = idx & 127;
      float a = 0.f;
      for (int e2=0;e2<128;++e2) a += h[sb*128+e2]*Wh[j*128+e2];
      float base = a + bh[j] + bx[j];
      float tw   = wxt[j] + wht[j];
      for (int ti=0; ti<5; ++ti)
        hbt[(ti*16+sb)*128 + j] = base + 0.25f*(float)ti*tw;   // t in {0,.25,.5,.75,1}
    }
  } else {
    if (t < 128){
      float a = 0.f;
      for (int i=0;i<128;++i) a += W2[i*128+t]*Wx[t*128+i];
      cv[t] = a;
    }
  }
}

// ---------------- fused CNF main kernel ----------------
// Round-19 = round-16 retry with the L2-pollution fix. Round 16 proved
// 48KB LDS -> 30.5% occupancy but W2-from-L2 missed (1.33GB fetches):
// streaming emb/lp0/out traffic evicted the 32KB W2 from the 4MB per-XCD
// L2. Fix: non-temporal loads/stores on all stream-once data (emb, lp0,
// out) so W2 + hbt stay L2-resident. Structure: nt=2, f16 datapath, Wx in
// LDS (32KB) + 16KB bufs = 48KB -> 3 blocks/CU; W2 fragments from L2,
// prefetched under softplus (ping-pong through mm2).
__global__ __launch_bounds__(256, 3) void cnf_main(
    const float* __restrict__ emb, const float* __restrict__ lp0,
    const float* __restrict__ b2g, const float* __restrict__ hbt,
    const float* __restrict__ cg,  const unsigned short* __restrict__ wxb,
    const unsigned short* __restrict__ w2b, float* __restrict__ out)
{
  __shared__ __align__(16) unsigned short sWx[16384];
  __shared__ __align__(16) unsigned short sT[4][2048];   // per-tile timeshared z^T/sp^T (4KB)

  const int tid = threadIdx.x;
  const int rowbase = blockIdx.x*64;

  // stage Wx into LDS: plain linear copy (layout already fragment-linear)
  for (int it=0; it<8; ++it){
    int L = it*4096 + tid*16;
    *(int4*)((char*)sWx + L) = *(const int4*)((const char*)wxb + L);
  }
  __syncthreads();

  const int w = tid>>6, tg = w>>1, hw = w&1, l = tid&63, q = l&15, g = l>>4;
  char* zB0 = (char*)&sT[2*tg][0];
  char* zB1 = (char*)&sT[2*tg+1][0];
  const char* wxBase = (const char*)sWx + hw*16384 + l*16;       // + (j*4+kc)*1024 imm
  const char* w2p    = (const char*)w2b + hw*16384 + l*16;       // global, L2-resident
  const int cwB = q*16 + 8*(g&1) + 256*(g>>1);  // transpose write base (bytes), + slot*512
  const int crB = g*256 + q*16;                 // transpose read base (bytes), + kc*1024
  const int hof = hw*64 + 4*g;                  // h/e base for this wave: + 16*j + r

  const int row0 = rowbase + tg*32 + q;
  const int row1 = row0 + 16;
  const int sb0 = row0/TTOK, tt0 = row0 - sb0*TTOK;
  const int sb1 = row1/TTOK, tt1 = row1 - sb1*TTOK;

  h2 zbp0[4][2], zbp1[4][2];   // z state, packed f16 (16 VGPRs)
  h2 ksp0[4][2], ksp1[4][2];   // RK4 running sum, packed f16 (16 VGPRs)
  f32x4 wk0[4], wk1[4];        // f32 accumulators
  f32x4 b2r[4];                // persistent b2
  float dlt0 = 0.f, dlt1 = 0.f;

  #pragma unroll
  for (int j=0; j<4; ++j){
    f32x4 e0 = __builtin_nontemporal_load((const f32x4*)(emb + tt0*128 + hof + 16*j));
    f32x4 e1 = __builtin_nontemporal_load((const f32x4*)(emb + tt1*128 + hof + 16*j));
    zbp0[j][0] = pkh(e0[0], e0[1]);
    zbp0[j][1] = pkh(e0[2], e0[3]);
    zbp1[j][0] = pkh(e1[0], e1[1]);
    zbp1[j][1] = pkh(e1[2], e1[3]);
    wk0[j] = (f32x4){0.f,0.f,0.f,0.f};
    wk1[j] = (f32x4){0.f,0.f,0.f,0.f};
    ksp0[j][0] = (h2){0,0}; ksp0[j][1] = (h2){0,0};
    ksp1[j][0] = (h2){0,0}; ksp1[j][1] = (h2){0,0};
    b2r[j] = *(const f32x4*)(b2g + hof + 16*j);
  }

  #pragma unroll 1
  for (int se=0; se<8; ++se){
    const int   s    = se>>2, e = se&3;
    const float coef = (e==0)?0.f:((e==3)?0.5f:0.25f); // z_eval = z_base + coef*k_prev
    const float we   = (e==1||e==2)?2.f:1.f;
    const int   ti   = 2*s + ((e==0)?0:((e<3)?1:2));
    const _Float16 ch = (_Float16)coef;
    const h2 coef2 = {ch, ch};
    const _Float16 wh_ = (_Float16)we;
    const h2 we2 = {wh_, wh_};
    const h2 c12 = {(_Float16)(1.f/12.f), (_Float16)(1.f/12.f)};

    // ---- phase 1: prefetch hb seeds; pack z_eval (both tiles) -> z^T buffers
    f32x4 hb0[4], hb1[4];
    {
      const float* p0 = hbt + (ti*16 + sb0)*128 + hof;
      const float* p1 = hbt + (ti*16 + sb1)*128 + hof;
      #pragma unroll
      for (int j=0; j<4; ++j){
        hb0[j] = *(const f32x4*)(p0 + 16*j);
        hb1[j] = *(const f32x4*)(p1 + 16*j);
      }
    }
    #pragma unroll
    for (int j=0; j<4; ++j){
      u32x2 wv0, wv1;
      if (e==0){
        wv0[0] = h2u(zbp0[j][0]); wv0[1] = h2u(zbp0[j][1]);
        wv1[0] = h2u(zbp1[j][0]); wv1[1] = h2u(zbp1[j][1]);
      } else {
        h2 a0 = pkh(wk0[j][0], wk0[j][1]);
        h2 a1 = pkh(wk0[j][2], wk0[j][3]);
        h2 z0 = coef2*a0 + zbp0[j][0];
        h2 z1 = coef2*a1 + zbp0[j][1];
        wv0[0] = h2u(z0); wv0[1] = h2u(z1);
        h2 b0 = pkh(wk1[j][0], wk1[j][1]);
        h2 b1 = pkh(wk1[j][2], wk1[j][3]);
        h2 y0 = coef2*b0 + zbp1[j][0];
        h2 y1 = coef2*b1 + zbp1[j][1];
        wv1[0] = h2u(y0); wv1[1] = h2u(y1);
      }
      int W = (hw*4+j)*512 + cwB;
      W ^= ((W>>8)&7)<<4;
      *(u32x2*)(zB0 + W) = wv0;
      *(u32x2*)(zB1 + W) = wv1;
    }
    SBAR();
    __syncthreads();   // z^T complete (both halves, both tiles)

    // ---- phase 3: matmul1 (h-half, both tiles): seed = prefetched hb
    #pragma unroll
    for (int j=0; j<4; ++j){ wk0[j] = hb0[j]; wk1[j] = hb1[j]; }
    #pragma unroll
    for (int kc=0; kc<4; ++kc){
      int R = kc*1024 + crB;
      R ^= ((R>>8)&7)<<4;
      f16x8 zf0 = *(const f16x8*)(zB0 + R);
      f16x8 zf1 = *(const f16x8*)(zB1 + R);
      #pragma unroll
      for (int j=0; j<4; ++j){
        f16x8 af = *(const f16x8*)(wxBase + (j*4+kc)*1024);
        wk0[j] = __builtin_amdgcn_mfma_f32_16x16x32_f16(af, zf0, wk0[j], 0,0,0);
        wk1[j] = __builtin_amdgcn_mfma_f32_16x16x32_f16(af, zf1, wk1[j], 0,0,0);
      }
      SBAR();
    }
    __syncthreads();   // z^T reads done; buffers free for sp^T

    // ---- phase 4: prefetch W2 frags kc0/1 (L2 latency hides under softplus);
    //               softplus both tiles -> sp^T buffers, sigmoid*c -> div
    f16x8 afA[4], afB[4];
    #pragma unroll
    for (int j=0; j<4; ++j) afA[j] = *(const f16x8*)(w2p + (j*4+0)*1024);
    #pragma unroll
    for (int j=0; j<4; ++j) afB[j] = *(const f16x8*)(w2p + (j*4+1)*1024);
    float dv0 = 0.f, dv1 = 0.f;
    #pragma unroll
    for (int j=0; j<4; ++j){
      f32x4 cc = *(const f32x4*)(cg + hof + 16*j);
      float sp0[4], sp1[4];
      #pragma unroll
      for (int r=0;r<4;++r){
        float x  = wk0[j][r];
        float ax = __builtin_fabsf(x);
        float ea = __expf(-ax);
        float opa = 1.0f + ea;
        float rc = __builtin_amdgcn_rcpf(opa);
        float lg = __logf(opa);
        sp0[r] = fmaxf(x,0.f) + lg;
        float sg = (x >= 0.f) ? rc : ea*rc;
        dv0 += sg*cc[r];
        float y  = wk1[j][r];
        float ay = __builtin_fabsf(y);
        float eb = __expf(-ay);
        float opb = 1.0f + eb;
        float rb = __builtin_amdgcn_rcpf(opb);
        float lb = __logf(opb);
        sp1[r] = fmaxf(y,0.f) + lb;
        float sh = (y >= 0.f) ? rb : eb*rb;
        dv1 += sh*cc[r];
      }
      int W = (hw*4+j)*512 + cwB;
      W ^= ((W>>8)&7)<<4;
      u32x2 wv0 = { h2u(pkh(sp0[0],sp0[1])), h2u(pkh(sp0[2],sp0[3])) };
      u32x2 wv1 = { h2u(pkh(sp1[0],sp1[1])), h2u(pkh(sp1[2],sp1[3])) };
      *(u32x2*)(zB0 + W) = wv0;
      *(u32x2*)(zB1 + W) = wv1;
    }
    dlt0 += we*dv0;
    dlt1 += we*dv1;
    SBAR();
    __syncthreads();   // sp^T complete

    // ---- phase 5: matmul2 (o-half, both tiles): W2 frags from L2, ping-pong
    #pragma unroll
    for (int j=0; j<4; ++j){ wk0[j] = b2r[j]; wk1[j] = b2r[j]; }
    #pragma unroll
    for (int kc=0; kc<4; ++kc){
      int R = kc*1024 + crB;
      R ^= ((R>>8)&7)<<4;
      f16x8 sf0 = *(const f16x8*)(zB0 + R);
      f16x8 sf1 = *(const f16x8*)(zB1 + R);
      #pragma unroll
      for (int j=0; j<4; ++j){
        f16x8 af = (kc&1) ? afB[j] : afA[j];
        wk0[j] = __builtin_amdgcn_mfma_f32_16x16x32_f16(af, sf0, wk0[j], 0,0,0);
        wk1[j] = __builtin_amdgcn_mfma_f32_16x16x32_f16(af, sf1, wk1[j], 0,0,0);
      }
      if (kc==0){
        #pragma unroll
        for (int j=0; j<4; ++j) afA[j] = *(const f16x8*)(w2p + (j*4+2)*1024);
      } else if (kc==1){
        #pragma unroll
        for (int j=0; j<4; ++j) afB[j] = *(const f16x8*)(w2p + (j*4+3)*1024);
      }
    }
    SBAR();

    // ---- phase 6: RK4 accumulate (both tiles; wk = k_e), packed f16
    if (e==0){
      #pragma unroll
      for (int j=0;j<4;++j){
        ksp0[j][0] = pkh(wk0[j][0], wk0[j][1]);
        ksp0[j][1] = pkh(wk0[j][2], wk0[j][3]);
        ksp1[j][0] = pkh(wk1[j][0], wk1[j][1]);
        ksp1[j][1] = pkh(wk1[j][2], wk1[j][3]);
      }
    } else if (e<3){
      #pragma unroll
      for (int j=0;j<4;++j){
        ksp0[j][0] = we2*pkh(wk0[j][0], wk0[j][1]) + ksp0[j][0];
        ksp0[j][1] = we2*pkh(wk0[j][2], wk0[j][3]) + ksp0[j][1];
        ksp1[j][0] = we2*pkh(wk1[j][0], wk1[j][1]) + ksp1[j][0];
        ksp1[j][1] = we2*pkh(wk1[j][2], wk1[j][3]) + ksp1[j][1];
      }
    } else {
      #pragma unroll
      for (int j=0;j<4;++j){
        h2 t00 = ksp0[j][0] + pkh(wk0[j][0], wk0[j][1]);
        h2 t01 = ksp0[j][1] + pkh(wk0[j][2], wk0[j][3]);
        zbp0[j][0] = c12*t00 + zbp0[j][0];
        zbp0[j][1] = c12*t01 + zbp0[j][1];
        h2 t10 = ksp1[j][0] + pkh(wk1[j][0], wk1[j][1]);
        h2 t11 = ksp1[j][1] + pkh(wk1[j][2], wk1[j][3]);
        zbp1[j][0] = c12*t10 + zbp1[j][0];
        zbp1[j][1] = c12*t11 + zbp1[j][1];
      }
    }
    SBAR();
    __syncthreads();   // sp^T reads done; buffers free for next eval's z^T
  }

  // ---- epilogue: g-reduce div partials, cross-wave combine via LDS (reuse zB0)
  {
    float d0 = dlt0, d1 = dlt1;
    d0 += __shfl_xor(d0, 16, 64);
    d0 += __shfl_xor(d0, 32, 64);
    d1 += __shfl_xor(d1, 16, 64);
    d1 += __shfl_xor(d1, 32, 64);
    float* fDv = (float*)zB0;
    if (g==0){
      fDv[hw*16 + q]      = d0;
      fDv[32 + hw*16 + q] = d1;
    }
    __syncthreads();
    if (hw==0 && g==0){
      float t0 = (fDv[q] + fDv[16+q]) * (1.f/12.f);
      float t1 = (fDv[32+q] + fDv[48+q]) * (1.f/12.f);
      float l0 = __builtin_nontemporal_load(lp0 + row0);
      float l1 = __builtin_nontemporal_load(lp0 + row1);
      __builtin_nontemporal_store(l0 - t0, out + row0);
      __builtin_nontemporal_store(l1 - t1, out + row1);
    }
  }
}

extern "C" void kernel_launch(void* const* d_in, const int* in_sizes, int n_in,
                              void* d_out, int out_size, void* d_ws, size_t ws_size,
                              hipStream_t stream) {
  const float* h    = (const float*)d_in[0];
  const float* emb  = (const float*)d_in[1];
  const float* lp0  = (const float*)d_in[2];
  const float* Wx   = (const float*)d_in[3];
  const float* wxt  = (const float*)d_in[4];
  const float* bx   = (const float*)d_in[5];
  const float* Wh   = (const float*)d_in[6];
  const float* wht  = (const float*)d_in[7];
  const float* bh   = (const float*)d_in[8];
  const float* W2   = (const float*)d_in[9];
  const float* b2   = (const float*)d_in[10];
  float* out = (float*)d_out;

  char* ws = (char*)d_ws;
  float* hbt          = (float*)ws;            // 5*16*128 f32 = 40960 B
  float* cv           = (float*)(ws + 40960);  // 128 f32     = 512 B
  unsigned short* wxb = (unsigned short*)(ws + 41472); // 16384 f16 = 32768 B
  unsigned short* w2b = (unsigned short*)(ws + 74240); // 16384 f16 = 32768 B

  cnf_prep<<<19, 256, 0, stream>>>(h, Wx, wxt, bx, Wh, wht, bh, W2, hbt, cv, wxb, w2b);
  cnf_main<<<2500, 256, 0, stream>>>(emb, lp0, b2, hbt, cv, wxb, w2b, out);
}

// Round 20
// 276.225 us; speedup vs baseline: 2.3759x; 2.3759x over previous
//
#include <hip/hip_runtime.h>

typedef __attribute__((ext_vector_type(4))) float f32x4;
typedef __attribute__((ext_vector_type(2))) unsigned int u32x2;
typedef _Float16 f16x8 __attribute__((ext_vector_type(8)));
typedef _Float16 h2    __attribute__((ext_vector_type(2)));

#define TTOK 10000
#define SBAR() __builtin_amdgcn_sched_barrier(0)

__device__ __forceinline__ h2 pkh(float lo, float hi){
  auto t = __builtin_amdgcn_cvt_pkrtz(lo, hi);   // __fp16 x2 -> bitcast to h2
  union{ decltype(t) a; h2 b; } c; c.a = t; return c.b;
}
__device__ __forceinline__ unsigned h2u(h2 v){ union{h2 h; unsigned u;} c; c.h=v; return c.u; }

__device__ __forceinline__ unsigned short f2h(float f){
  _Float16 h = (_Float16)f;                 // RNE
  union{_Float16 h; unsigned short u;} c; c.h = h; return c.u;
}

// ---------------- prep: fragment-linear f16 weights, hb+t*tw seeds, c ----------------
// wb[((jj*4+kc)*64 + l)*8 + i] = W[jj*16+q][kc*32+g*8+i], l=g*16+q: a wave's
// 16B/lane fragment read is 64 lanes x contiguous = 1024B (conflict-free),
// address = base + immediate (round 13, verified).
__global__ void cnf_prep(const float* __restrict__ h, const float* __restrict__ Wx,
                         const float* __restrict__ wxt, const float* __restrict__ bx,
                         const float* __restrict__ Wh, const float* __restrict__ wht,
                         const float* __restrict__ bh, const float* __restrict__ W2,
                         float* __restrict__ hbt, float* __restrict__ cv,
                         unsigned short* __restrict__ wxb, unsigned short* __restrict__ w2b)
{
  const int b = blockIdx.x, t = threadIdx.x;
  if (b < 16) {
    const int jj = b & 7;
    const float* W = (b < 8) ? Wx : W2;
    unsigned short* dst = (b < 8) ? wxb : w2b;
    const int kc = t>>6, l = t&63, q = l&15, g = l>>4;
    #pragma unroll
    for (int i=0;i<8;++i)
      dst[((jj*4+kc)*64 + l)*8 + i] = f2h(W[(jj*16+q)*128 + kc*32 + g*8 + i]);
  } else if (b < 18) {
    for (int i=0;i<4;++i){
      int idx = i*256 + t;
      int sb = (b-16)*8 + (idx>>7);
      int j  = idx & 127;
      float a = 0.f;
      for (int e2=0;e2<128;++e2) a += h[sb*128+e2]*Wh[j*128+e2];
      float base = a + bh[j] + bx[j];
      float tw   = wxt[j] + wht[j];
      for (int ti=0; ti<5; ++ti)
        hbt[(ti*16+sb)*128 + j] = base + 0.25f*(float)ti*tw;   // t in {0,.25,.5,.75,1}
    }
  } else {
    if (t < 128){
      float a = 0.f;
      for (int i=0;i<128;++i) a += W2[i*128+t]*Wx[t*128+i];
      cv[t] = a;
    }
  }
}

// ---------------- fused CNF main kernel ----------------
// Round-20: 1024-thr block = 16 waves = 4 tile-pairs (tg) x 4-way h-split
// (hq owns 32 h/o cols). One 64KB weight copy amortized over 16 waves ->
// 16 waves/CU (2x round 17). f16 datapath shrinks per-thread demand to
// ~100 regs < the 128 cap that 4 waves/SIMD needs; (1024,4) pins the cap
// (round 12's (1024,1) let the allocator starve at 64). Separate z^T/sp^T
// buffers -> only 2 barriers/eval. LDS = 64KB weights + 64KB bufs = 128KB,
// 1 block/CU. Grid 1250 (128 rows/block).
__global__ __launch_bounds__(1024, 4) void cnf_main(
    const float* __restrict__ emb, const float* __restrict__ lp0,
    const float* __restrict__ b2g, const float* __restrict__ hbt,
    const float* __restrict__ cg,  const unsigned short* __restrict__ wxb,
    const unsigned short* __restrict__ w2b, float* __restrict__ out)
{
  __shared__ __align__(16) unsigned short sWx[16384];
  __shared__ __align__(16) unsigned short sW2[16384];
  __shared__ __align__(16) unsigned short sZ[8][2048];   // per-tile z^T (4KB)
  __shared__ __align__(16) unsigned short sP[8][2048];   // per-tile sp^T (4KB)

  const int tid = threadIdx.x;
  const int rowbase = blockIdx.x*128;

  // stage weights into LDS: plain linear copy (layout already fragment-linear)
  for (int it=0; it<2; ++it){
    int L = it*16384 + tid*16;
    *(int4*)((char*)sWx + L) = *(const int4*)((const char*)wxb + L);
    *(int4*)((char*)sW2 + L) = *(const int4*)((const char*)w2b + L);
  }
  __syncthreads();

  const int w = tid>>6, tg = w>>2, hq = w&3, l = tid&63, q = l&15, g = l>>4;
  char* zB0 = (char*)&sZ[2*tg][0];
  char* zB1 = (char*)&sZ[2*tg+1][0];
  char* pB0 = (char*)&sP[2*tg][0];
  char* pB1 = (char*)&sP[2*tg+1][0];
  const char* wxBase = (const char*)sWx + hq*8192 + l*16;  // + (jl*4+kc)*1024 imm
  const char* w2Base = (const char*)sW2 + hq*8192 + l*16;
  const int cwB = q*16 + 8*(g&1) + 256*(g>>1);
  const int crB = g*256 + q*16;
  const int hof = hq*32 + 4*g;                  // h/e base: + 16*jl + r

  // loop-invariant swizzled LDS addresses
  int wadr[2], radr[4];
  #pragma unroll
  for (int jl=0; jl<2; ++jl){ int W = (hq*2+jl)*512 + cwB; W ^= ((W>>8)&7)<<4; wadr[jl] = W; }
  #pragma unroll
  for (int kc=0; kc<4; ++kc){ int R = kc*1024 + crB; R ^= ((R>>8)&7)<<4; radr[kc] = R; }

  const int row0 = rowbase + tg*32 + q;
  const int row1 = row0 + 16;
  const int sb0 = row0/TTOK, tt0 = row0 - sb0*TTOK;
  const int sb1 = row1/TTOK, tt1 = row1 - sb1*TTOK;

  h2 zbp0[2][2], zbp1[2][2];   // z state (this wave's 32-e slice), packed f16
  h2 ksp0[2][2], ksp1[2][2];   // RK4 running sum, packed f16
  f32x4 wk0[2], wk1[2];        // f32 accumulators
  f32x4 b2r[2], ccr[2];        // persistent b2, c slices
  float dlt0 = 0.f, dlt1 = 0.f;

  #pragma unroll
  for (int jl=0; jl<2; ++jl){
    f32x4 e0 = *(const f32x4*)(emb + tt0*128 + hof + 16*jl);
    f32x4 e1 = *(const f32x4*)(emb + tt1*128 + hof + 16*jl);
    zbp0[jl][0] = pkh(e0[0], e0[1]);  zbp0[jl][1] = pkh(e0[2], e0[3]);
    zbp1[jl][0] = pkh(e1[0], e1[1]);  zbp1[jl][1] = pkh(e1[2], e1[3]);
    wk0[jl] = (f32x4){0.f,0.f,0.f,0.f};
    wk1[jl] = (f32x4){0.f,0.f,0.f,0.f};
    ksp0[jl][0] = (h2){0,0}; ksp0[jl][1] = (h2){0,0};
    ksp1[jl][0] = (h2){0,0}; ksp1[jl][1] = (h2){0,0};
    b2r[jl] = *(const f32x4*)(b2g + hof + 16*jl);
    ccr[jl] = *(const f32x4*)(cg  + hof + 16*jl);
  }

  #pragma unroll 1
  for (int se=0; se<8; ++se){
    const int   s    = se>>2, e = se&3;
    const float coef = (e==0)?0.f:((e==3)?0.5f:0.25f); // z_eval = z_base + coef*k_prev
    const float we   = (e==1||e==2)?2.f:1.f;
    const int   ti   = 2*s + ((e==0)?0:((e<3)?1:2));
    const _Float16 ch = (_Float16)coef;
    const h2 coef2 = {ch, ch};
    const _Float16 wh_ = (_Float16)we;
    const h2 we2 = {wh_, wh_};
    const h2 c12 = {(_Float16)(1.f/12.f), (_Float16)(1.f/12.f)};

    // ---- phase 1: prefetch hb seeds; pack z_eval (both tiles) -> z^T buffers
    f32x4 hb0[2], hb1[2];
    {
      const float* p0 = hbt + (ti*16 + sb0)*128 + hof;
      const float* p1 = hbt + (ti*16 + sb1)*128 + hof;
      #pragma unroll
      for (int jl=0; jl<2; ++jl){
        hb0[jl] = *(const f32x4*)(p0 + 16*jl);
        hb1[jl] = *(const f32x4*)(p1 + 16*jl);
      }
    }
    #pragma unroll
    for (int jl=0; jl<2; ++jl){
      u32x2 wv0, wv1;
      if (e==0){
        wv0[0] = h2u(zbp0[jl][0]); wv0[1] = h2u(zbp0[jl][1]);
        wv1[0] = h2u(zbp1[jl][0]); wv1[1] = h2u(zbp1[jl][1]);
      } else {
        h2 a0 = pkh(wk0[jl][0], wk0[jl][1]);
        h2 a1 = pkh(wk0[jl][2], wk0[jl][3]);
        h2 z0 = coef2*a0 + zbp0[jl][0];
        h2 z1 = coef2*a1 + zbp0[jl][1];
        wv0[0] = h2u(z0); wv0[1] = h2u(z1);
        h2 b0 = pkh(wk1[jl][0], wk1[jl][1]);
        h2 b1 = pkh(wk1[jl][2], wk1[jl][3]);
        h2 y0 = coef2*b0 + zbp1[jl][0];
        h2 y1 = coef2*b1 + zbp1[jl][1];
        wv1[0] = h2u(y0); wv1[1] = h2u(y1);
      }
      *(u32x2*)(zB0 + wadr[jl]) = wv0;
      *(u32x2*)(zB1 + wadr[jl]) = wv1;
    }
    SBAR();
    __syncthreads();   // barrier 1: z^T complete (all 4 hq slices, both tiles)

    // ---- phase 2: matmul1 (32-h slice, both tiles): seed = prefetched hb
    #pragma unroll
    for (int jl=0; jl<2; ++jl){ wk0[jl] = hb0[jl]; wk1[jl] = hb1[jl]; }
    #pragma unroll
    for (int kc=0; kc<4; ++kc){
      f16x8 zf0 = *(const f16x8*)(zB0 + radr[kc]);
      f16x8 zf1 = *(const f16x8*)(zB1 + radr[kc]);
      #pragma unroll
      for (int jl=0; jl<2; ++jl){
        f16x8 af = *(const f16x8*)(wxBase + (jl*4+kc)*1024);
        wk0[jl] = __builtin_amdgcn_mfma_f32_16x16x32_f16(af, zf0, wk0[jl], 0,0,0);
        wk1[jl] = __builtin_amdgcn_mfma_f32_16x16x32_f16(af, zf1, wk1[jl], 0,0,0);
      }
      SBAR();
    }

    // ---- phase 3: softplus both tiles -> sp^T buffers, sigmoid*c -> div
    float dv0 = 0.f, dv1 = 0.f;
    #pragma unroll
    for (int jl=0; jl<2; ++jl){
      f32x4 cc = ccr[jl];
      float sp0[4], sp1[4];
      #pragma unroll
      for (int r=0;r<4;++r){
        float x  = wk0[jl][r];
        float ax = __builtin_fabsf(x);
        float ea = __expf(-ax);
        float opa = 1.0f + ea;
        float rc = __builtin_amdgcn_rcpf(opa);
        float lg = __logf(opa);
        sp0[r] = fmaxf(x,0.f) + lg;
        float sg = (x >= 0.f) ? rc : ea*rc;
        dv0 += sg*cc[r];
        float y  = wk1[jl][r];
        float ay = __builtin_fabsf(y);
        float eb = __expf(-ay);
        float opb = 1.0f + eb;
        float rb = __builtin_amdgcn_rcpf(opb);
        float lb = __logf(opb);
        sp1[r] = fmaxf(y,0.f) + lb;
        float sh = (y >= 0.f) ? rb : eb*rb;
        dv1 += sh*cc[r];
      }
      u32x2 wv0 = { h2u(pkh(sp0[0],sp0[1])), h2u(pkh(sp0[2],sp0[3])) };
      u32x2 wv1 = { h2u(pkh(sp1[0],sp1[1])), h2u(pkh(sp1[2],sp1[3])) };
      *(u32x2*)(pB0 + wadr[jl]) = wv0;
      *(u32x2*)(pB1 + wadr[jl]) = wv1;
    }
    dlt0 += we*dv0;
    dlt1 += we*dv1;
    SBAR();
    __syncthreads();   // barrier 2: sp^T complete

    // ---- phase 4: matmul2 (32-o slice, both tiles): seed = persistent b2
    #pragma unroll
    for (int jl=0; jl<2; ++jl){ wk0[jl] = b2r[jl]; wk1[jl] = b2r[jl]; }
    #pragma unroll
    for (int kc=0; kc<4; ++kc){
      f16x8 sf0 = *(const f16x8*)(pB0 + radr[kc]);
      f16x8 sf1 = *(const f16x8*)(pB1 + radr[kc]);
      #pragma unroll
      for (int jl=0; jl<2; ++jl){
        f16x8 af = *(const f16x8*)(w2Base + (jl*4+kc)*1024);
        wk0[jl] = __builtin_amdgcn_mfma_f32_16x16x32_f16(af, sf0, wk0[jl], 0,0,0);
        wk1[jl] = __builtin_amdgcn_mfma_f32_16x16x32_f16(af, sf1, wk1[jl], 0,0,0);
      }
      SBAR();
    }

    // ---- phase 5: RK4 accumulate (both tiles; wk = k_e), packed f16
    if (e==0){
      #pragma unroll
      for (int jl=0;jl<2;++jl){
        ksp0[jl][0] = pkh(wk0[jl][0], wk0[jl][1]);
        ksp0[jl][1] = pkh(wk0[jl][2], wk0[jl][3]);
        ksp1[jl][0] = pkh(wk1[jl][0], wk1[jl][1]);
        ksp1[jl][1] = pkh(wk1[jl][2], wk1[jl][3]);
      }
    } else if (e<3){
      #pragma unroll
      for (int jl=0;jl<2;++jl){
        ksp0[jl][0] = we2*pkh(wk0[jl][0], wk0[jl][1]) + ksp0[jl][0];
        ksp0[jl][1] = we2*pkh(wk0[jl][2], wk0[jl][3]) + ksp0[jl][1];
        ksp1[jl][0] = we2*pkh(wk1[jl][0], wk1[jl][1]) + ksp1[jl][0];
        ksp1[jl][1] = we2*pkh(wk1[jl][2], wk1[jl][3]) + ksp1[jl][1];
      }
    } else {
      #pragma unroll
      for (int jl=0;jl<2;++jl){
        h2 t00 = ksp0[jl][0] + pkh(wk0[jl][0], wk0[jl][1]);
        h2 t01 = ksp0[jl][1] + pkh(wk0[jl][2], wk0[jl][3]);
        zbp0[jl][0] = c12*t00 + zbp0[jl][0];
        zbp0[jl][1] = c12*t01 + zbp0[jl][1];
        h2 t10 = ksp1[jl][0] + pkh(wk1[jl][0], wk1[jl][1]);
        h2 t11 = ksp1[jl][1] + pkh(wk1[jl][2], wk1[jl][3]);
        zbp1[jl][0] = c12*t10 + zbp1[jl][0];
        zbp1[jl][1] = c12*t11 + zbp1[jl][1];
      }
    }
    SBAR();
  }

  // ---- epilogue: g-reduce div partials; cross-hq combine via LDS (reuse zB)
  {
    float d0 = dlt0, d1 = dlt1;
    d0 += __shfl_xor(d0, 16, 64);
    d0 += __shfl_xor(d0, 32, 64);
    d1 += __shfl_xor(d1, 16, 64);
    d1 += __shfl_xor(d1, 32, 64);
    float* f0 = (float*)zB0;
    float* f1 = (float*)zB1;
    if (g==0){
      f0[hq*16 + q] = d0;
      f1[hq*16 + q] = d1;
    }
    __syncthreads();
    if (hq==0 && g==0){
      float t0 = (f0[q] + f0[16+q] + f0[32+q] + f0[48+q]) * (1.f/12.f);
      float t1 = (f1[q] + f1[16+q] + f1[32+q] + f1[48+q]) * (1.f/12.f);
      out[row0] = lp0[row0] - t0;
      out[row1] = lp0[row1] - t1;
    }
  }
}

extern "C" void kernel_launch(void* const* d_in, const int* in_sizes, int n_in,
                              void* d_out, int out_size, void* d_ws, size_t ws_size,
                              hipStream_t stream) {
  const float* h    = (const float*)d_in[0];
  const float* emb  = (const float*)d_in[1];
  const float* lp0  = (const float*)d_in[2];
  const float* Wx   = (const float*)d_in[3];
  const float* wxt  = (const float*)d_in[4];
  const float* bx   = (const float*)d_in[5];
  const float* Wh   = (const float*)d_in[6];
  const float* wht  = (const float*)d_in[7];
  const float* bh   = (const float*)d_in[8];
  const float* W2   = (const float*)d_in[9];
  const float* b2   = (const float*)d_in[10];
  float* out = (float*)d_out;

  char* ws = (char*)d_ws;
  float* hbt          = (float*)ws;            // 5*16*128 f32 = 40960 B
  float* cv           = (float*)(ws + 40960);  // 128 f32     = 512 B
  unsigned short* wxb = (unsigned short*)(ws + 41472); // 16384 f16 = 32768 B
  unsigned short* w2b = (unsigned short*)(ws + 74240); // 16384 f16 = 32768 B

  cnf_prep<<<19, 256, 0, stream>>>(h, Wx, wxt, bx, Wh, wht, bh, W2, hbt, cv, wxb, w2b);
  cnf_main<<<1250, 1024, 0, stream>>>(emb, lp0, b2, hbt, cv, wxb, w2b, out);
}

// Round 21
// 204.124 us; speedup vs baseline: 3.2151x; 1.3532x over previous
//
#include <hip/hip_runtime.h>

typedef __attribute__((ext_vector_type(4))) float f32x4;
typedef __attribute__((ext_vector_type(2))) unsigned int u32x2;
typedef _Float16 f16x8 __attribute__((ext_vector_type(8)));
typedef _Float16 h2    __attribute__((ext_vector_type(2)));

#define TTOK 10000
#define SBAR() __builtin_amdgcn_sched_barrier(0)

__device__ __forceinline__ h2 pkh(float lo, float hi){
  auto t = __builtin_amdgcn_cvt_pkrtz(lo, hi);   // __fp16 x2 -> bitcast to h2
  union{ decltype(t) a; h2 b; } c; c.a = t; return c.b;
}
__device__ __forceinline__ unsigned h2u(h2 v){ union{h2 h; unsigned u;} c; c.h=v; return c.u; }

__device__ __forceinline__ unsigned short f2h(float f){
  _Float16 h = (_Float16)f;                 // RNE
  union{_Float16 h; unsigned short u;} c; c.h = h; return c.u;
}

// ---------------- prep: fragment-linear f16 weights, hb+t*tw seeds, c ----------------
// wb[((jj*4+kc)*64 + l)*8 + i] = W[jj*16+q][kc*32+g*8+i], l=g*16+q: a wave's
// 16B/lane fragment read is 64 lanes x contiguous = 1024B (conflict-free),
// address = base + immediate (round 13, verified).
__global__ void cnf_prep(const float* __restrict__ h, const float* __restrict__ Wx,
                         const float* __restrict__ wxt, const float* __restrict__ bx,
                         const float* __restrict__ Wh, const float* __restrict__ wht,
                         const float* __restrict__ bh, const float* __restrict__ W2,
                         float* __restrict__ hbt, float* __restrict__ cv,
                         unsigned short* __restrict__ wxb, unsigned short* __restrict__ w2b)
{
  const int b = blockIdx.x, t = threadIdx.x;
  if (b < 16) {
    const int jj = b & 7;
    const float* W = (b < 8) ? Wx : W2;
    unsigned short* dst = (b < 8) ? wxb : w2b;
    const int kc = t>>6, l = t&63, q = l&15, g = l>>4;
    #pragma unroll
    for (int i=0;i<8;++i)
      dst[((jj*4+kc)*64 + l)*8 + i] = f2h(W[(jj*16+q)*128 + kc*32 + g*8 + i]);
  } else if (b < 18) {
    for (int i=0;i<4;++i){
      int idx = i*256 + t;
      int sb = (b-16)*8 + (idx>>7);
      int j  = idx & 127;
      float a = 0.f;
      for (int e2=0;e2<128;++e2) a += h[sb*128+e2]*Wh[j*128+e2];
      float base = a + bh[j] + bx[j];
      float tw   = wxt[j] + wht[j];
      for (int ti=0; ti<5; ++ti)
        hbt[(ti*16+sb)*128 + j] = base + 0.25f*(float)ti*tw;   // t in {0,.25,.5,.75,1}
    }
  } else {
    if (t < 128){
      float a = 0.f;
      for (int i=0;i<128;++i) a += W2[i*128+t]*Wx[t*128+i];
      cv[t] = a;
    }
  }
}

// ---------------- fused CNF main kernel ----------------
// Round-21 = round-17 champion (nt=2 h-split, both weights in LDS, f16
// packed datapath, 80KB -> 2 blocks/CU) + (a) s_setprio(1) around MFMA
// clusters (2 blocks/CU at staggered phases -> scheduler favors the
// MFMA-issuing wave while the other block's waves run softplus VALU),
// (b) c vector hoisted to persistent registers (8 fewer global loads/eval).
// Structure validated as local optimum: r18 (no barriers), r19 (W2 from
// L2), r20 (16-wave block) all regressed.
__global__ __launch_bounds__(256, 2) void cnf_main(
    const float* __restrict__ emb, const float* __restrict__ lp0,
    const float* __restrict__ b2g, const float* __restrict__ hbt,
    const float* __restrict__ cg,  const unsigned short* __restrict__ wxb,
    const unsigned short* __restrict__ w2b, float* __restrict__ out)
{
  __shared__ __align__(16) unsigned short sWx[16384];
  __shared__ __align__(16) unsigned short sW2[16384];
  __shared__ __align__(16) unsigned short sT[4][2048];   // per-tile timeshared z^T/sp^T (4KB)

  const int tid = threadIdx.x;
  const int rowbase = blockIdx.x*64;

  // stage weights into LDS: plain linear copy (layout already fragment-linear)
  for (int it=0; it<8; ++it){
    int L = it*4096 + tid*16;
    *(int4*)((char*)sWx + L) = *(const int4*)((const char*)wxb + L);
    *(int4*)((char*)sW2 + L) = *(const int4*)((const char*)w2b + L);
  }
  __syncthreads();

  const int w = tid>>6, tg = w>>1, hw = w&1, l = tid&63, q = l&15, g = l>>4;
  char* zB0 = (char*)&sT[2*tg][0];
  char* zB1 = (char*)&sT[2*tg+1][0];
  const char* wxBase = (const char*)sWx + hw*16384 + l*16;  // + (j*4+kc)*1024 imm
  const char* w2Base = (const char*)sW2 + hw*16384 + l*16;
  const int cwB = q*16 + 8*(g&1) + 256*(g>>1);  // transpose write base (bytes), + slot*512
  const int crB = g*256 + q*16;                 // transpose read base (bytes), + kc*1024
  const int hof = hw*64 + 4*g;                  // h/e base for this wave: + 16*j + r

  const int row0 = rowbase + tg*32 + q;
  const int row1 = row0 + 16;
  const int sb0 = row0/TTOK, tt0 = row0 - sb0*TTOK;
  const int sb1 = row1/TTOK, tt1 = row1 - sb1*TTOK;

  h2 zbp0[4][2], zbp1[4][2];   // z state, packed f16 (16 VGPRs)
  h2 ksp0[4][2], ksp1[4][2];   // RK4 running sum, packed f16 (16 VGPRs)
  f32x4 wk0[4], wk1[4];        // f32 accumulators
  f32x4 b2r[4], ccr[4];        // persistent b2, c
  float dlt0 = 0.f, dlt1 = 0.f;

  #pragma unroll
  for (int j=0; j<4; ++j){
    f32x4 e0 = *(const f32x4*)(emb + tt0*128 + hof + 16*j);
    f32x4 e1 = *(const f32x4*)(emb + tt1*128 + hof + 16*j);
    zbp0[j][0] = pkh(e0[0], e0[1]);
    zbp0[j][1] = pkh(e0[2], e0[3]);
    zbp1[j][0] = pkh(e1[0], e1[1]);
    zbp1[j][1] = pkh(e1[2], e1[3]);
    wk0[j] = (f32x4){0.f,0.f,0.f,0.f};
    wk1[j] = (f32x4){0.f,0.f,0.f,0.f};
    ksp0[j][0] = (h2){0,0}; ksp0[j][1] = (h2){0,0};
    ksp1[j][0] = (h2){0,0}; ksp1[j][1] = (h2){0,0};
    b2r[j] = *(const f32x4*)(b2g + hof + 16*j);
    ccr[j] = *(const f32x4*)(cg  + hof + 16*j);
  }

  #pragma unroll 1
  for (int se=0; se<8; ++se){
    const int   s    = se>>2, e = se&3;
    const float coef = (e==0)?0.f:((e==3)?0.5f:0.25f); // z_eval = z_base + coef*k_prev
    const float we   = (e==1||e==2)?2.f:1.f;
    const int   ti   = 2*s + ((e==0)?0:((e<3)?1:2));
    const _Float16 ch = (_Float16)coef;
    const h2 coef2 = {ch, ch};
    const _Float16 wh_ = (_Float16)we;
    const h2 we2 = {wh_, wh_};
    const h2 c12 = {(_Float16)(1.f/12.f), (_Float16)(1.f/12.f)};

    // ---- phase 1: prefetch hb seeds; pack z_eval (both tiles) -> z^T buffers
    f32x4 hb0[4], hb1[4];
    {
      const float* p0 = hbt + (ti*16 + sb0)*128 + hof;
      const float* p1 = hbt + (ti*16 + sb1)*128 + hof;
      #pragma unroll
      for (int j=0; j<4; ++j){
        hb0[j] = *(const f32x4*)(p0 + 16*j);
        hb1[j] = *(const f32x4*)(p1 + 16*j);
      }
    }
    #pragma unroll
    for (int j=0; j<4; ++j){
      u32x2 wv0, wv1;
      if (e==0){
        wv0[0] = h2u(zbp0[j][0]); wv0[1] = h2u(zbp0[j][1]);
        wv1[0] = h2u(zbp1[j][0]); wv1[1] = h2u(zbp1[j][1]);
      } else {
        h2 a0 = pkh(wk0[j][0], wk0[j][1]);
        h2 a1 = pkh(wk0[j][2], wk0[j][3]);
        h2 z0 = coef2*a0 + zbp0[j][0];
        h2 z1 = coef2*a1 + zbp0[j][1];
        wv0[0] = h2u(z0); wv0[1] = h2u(z1);
        h2 b0 = pkh(wk1[j][0], wk1[j][1]);
        h2 b1 = pkh(wk1[j][2], wk1[j][3]);
        h2 y0 = coef2*b0 + zbp1[j][0];
        h2 y1 = coef2*b1 + zbp1[j][1];
        wv1[0] = h2u(y0); wv1[1] = h2u(y1);
      }
      int W = (hw*4+j)*512 + cwB;
      W ^= ((W>>8)&7)<<4;
      *(u32x2*)(zB0 + W) = wv0;
      *(u32x2*)(zB1 + W) = wv1;
    }
    SBAR();
    __syncthreads();   // z^T complete (both halves, both tiles)

    // ---- phase 3: matmul1 (h-half, both tiles): seed = prefetched hb
    #pragma unroll
    for (int j=0; j<4; ++j){ wk0[j] = hb0[j]; wk1[j] = hb1[j]; }
    __builtin_amdgcn_s_setprio(1);
    #pragma unroll
    for (int kc=0; kc<4; ++kc){
      int R = kc*1024 + crB;
      R ^= ((R>>8)&7)<<4;
      f16x8 zf0 = *(const f16x8*)(zB0 + R);
      f16x8 zf1 = *(const f16x8*)(zB1 + R);
      #pragma unroll
      for (int j=0; j<4; ++j){
        f16x8 af = *(const f16x8*)(wxBase + (j*4+kc)*1024);
        wk0[j] = __builtin_amdgcn_mfma_f32_16x16x32_f16(af, zf0, wk0[j], 0,0,0);
        wk1[j] = __builtin_amdgcn_mfma_f32_16x16x32_f16(af, zf1, wk1[j], 0,0,0);
      }
      SBAR();
    }
    __builtin_amdgcn_s_setprio(0);
    __syncthreads();   // z^T reads done; buffers free for sp^T

    // ---- phase 4: softplus both tiles -> sp^T buffers, sigmoid*c -> div
    float dv0 = 0.f, dv1 = 0.f;
    #pragma unroll
    for (int j=0; j<4; ++j){
      f32x4 cc = ccr[j];
      float sp0[4], sp1[4];
      #pragma unroll
      for (int r=0;r<4;++r){
        float x  = wk0[j][r];
        float ax = __builtin_fabsf(x);
        float ea = __expf(-ax);
        float opa = 1.0f + ea;
        float rc = __builtin_amdgcn_rcpf(opa);
        float lg = __logf(opa);
        sp0[r] = fmaxf(x,0.f) + lg;
        float sg = (x >= 0.f) ? rc : ea*rc;
        dv0 += sg*cc[r];
        float y  = wk1[j][r];
        float ay = __builtin_fabsf(y);
        float eb = __expf(-ay);
        float opb = 1.0f + eb;
        float rb = __builtin_amdgcn_rcpf(opb);
        float lb = __logf(opb);
        sp1[r] = fmaxf(y,0.f) + lb;
        float sh = (y >= 0.f) ? rb : eb*rb;
        dv1 += sh*cc[r];
      }
      int W = (hw*4+j)*512 + cwB;
      W ^= ((W>>8)&7)<<4;
      u32x2 wv0 = { h2u(pkh(sp0[0],sp0[1])), h2u(pkh(sp0[2],sp0[3])) };
      u32x2 wv1 = { h2u(pkh(sp1[0],sp1[1])), h2u(pkh(sp1[2],sp1[3])) };
      *(u32x2*)(zB0 + W) = wv0;
      *(u32x2*)(zB1 + W) = wv1;
    }
    dlt0 += we*dv0;
    dlt1 += we*dv1;
    SBAR();
    __syncthreads();   // sp^T complete

    // ---- phase 5: matmul2 (o-half, both tiles): seed = persistent b2
    #pragma unroll
    for (int j=0; j<4; ++j){ wk0[j] = b2r[j]; wk1[j] = b2r[j]; }
    __builtin_amdgcn_s_setprio(1);
    #pragma unroll
    for (int kc=0; kc<4; ++kc){
      int R = kc*1024 + crB;
      R ^= ((R>>8)&7)<<4;
      f16x8 sf0 = *(const f16x8*)(zB0 + R);
      f16x8 sf1 = *(const f16x8*)(zB1 + R);
      #pragma unroll
      for (int j=0; j<4; ++j){
        f16x8 af = *(const f16x8*)(w2Base + (j*4+kc)*1024);
        wk0[j] = __builtin_amdgcn_mfma_f32_16x16x32_f16(af, sf0, wk0[j], 0,0,0);
        wk1[j] = __builtin_amdgcn_mfma_f32_16x16x32_f16(af, sf1, wk1[j], 0,0,0);
      }
      SBAR();
    }
    __builtin_amdgcn_s_setprio(0);

    // ---- phase 6: RK4 accumulate (both tiles; wk = k_e), packed f16
    if (e==0){
      #pragma unroll
      for (int j=0;j<4;++j){
        ksp0[j][0] = pkh(wk0[j][0], wk0[j][1]);
        ksp0[j][1] = pkh(wk0[j][2], wk0[j][3]);
        ksp1[j][0] = pkh(wk1[j][0], wk1[j][1]);
        ksp1[j][1] = pkh(wk1[j][2], wk1[j][3]);
      }
    } else if (e<3){
      #pragma unroll
      for (int j=0;j<4;++j){
        ksp0[j][0] = we2*pkh(wk0[j][0], wk0[j][1]) + ksp0[j][0];
        ksp0[j][1] = we2*pkh(wk0[j][2], wk0[j][3]) + ksp0[j][1];
        ksp1[j][0] = we2*pkh(wk1[j][0], wk1[j][1]) + ksp1[j][0];
        ksp1[j][1] = we2*pkh(wk1[j][2], wk1[j][3]) + ksp1[j][1];
      }
    } else {
      #pragma unroll
      for (int j=0;j<4;++j){
        h2 t00 = ksp0[j][0] + pkh(wk0[j][0], wk0[j][1]);
        h2 t01 = ksp0[j][1] + pkh(wk0[j][2], wk0[j][3]);
        zbp0[j][0] = c12*t00 + zbp0[j][0];
        zbp0[j][1] = c12*t01 + zbp0[j][1];
        h2 t10 = ksp1[j][0] + pkh(wk1[j][0], wk1[j][1]);
        h2 t11 = ksp1[j][1] + pkh(wk1[j][2], wk1[j][3]);
        zbp1[j][0] = c12*t10 + zbp1[j][0];
        zbp1[j][1] = c12*t11 + zbp1[j][1];
      }
    }
    SBAR();
    __syncthreads();   // sp^T reads done; buffers free for next eval's z^T
  }

  // ---- epilogue: g-reduce div partials, cross-wave combine via LDS (reuse zB0)
  {
    float d0 = dlt0, d1 = dlt1;
    d0 += __shfl_xor(d0, 16, 64);
    d0 += __shfl_xor(d0, 32, 64);
    d1 += __shfl_xor(d1, 16, 64);
    d1 += __shfl_xor(d1, 32, 64);
    float* fDv = (float*)zB0;
    if (g==0){
      fDv[hw*16 + q]      = d0;
      fDv[32 + hw*16 + q] = d1;
    }
    __syncthreads();
    if (hw==0 && g==0){
      float t0 = (fDv[q] + fDv[16+q]) * (1.f/12.f);
      float t1 = (fDv[32+q] + fDv[48+q]) * (1.f/12.f);
      out[row0] = lp0[row0] - t0;
      out[row1] = lp0[row1] - t1;
    }
  }
}

extern "C" void kernel_launch(void* const* d_in, const int* in_sizes, int n_in,
                              void* d_out, int out_size, void* d_ws, size_t ws_size,
                              hipStream_t stream) {
  const float* h    = (const float*)d_in[0];
  const float* emb  = (const float*)d_in[1];
  const float* lp0  = (const float*)d_in[2];
  const float* Wx   = (const float*)d_in[3];
  const float* wxt  = (const float*)d_in[4];
  const float* bx   = (const float*)d_in[5];
  const float* Wh   = (const float*)d_in[6];
  const float* wht  = (const float*)d_in[7];
  const float* bh   = (const float*)d_in[8];
  const float* W2   = (const float*)d_in[9];
  const float* b2   = (const float*)d_in[10];
  float* out = (float*)d_out;

  char* ws = (char*)d_ws;
  float* hbt          = (float*)ws;            // 5*16*128 f32 = 40960 B
  float* cv           = (float*)(ws + 40960);  // 128 f32     = 512 B
  unsigned short* wxb = (unsigned short*)(ws + 41472); // 16384 f16 = 32768 B
  unsigned short* w2b = (unsigned short*)(ws + 74240); // 16384 f16 = 32768 B

  cnf_prep<<<19, 256, 0, stream>>>(h, Wx, wxt, bx, Wh, wht, bh, W2, hbt, cv, wxb, w2b);
  cnf_main<<<2500, 256, 0, stream>>>(emb, lp0, b2, hbt, cv, wxb, w2b, out);
}

// Round 22
// 161.539 us; speedup vs baseline: 4.0627x; 1.2636x over previous
//
#include <hip/hip_runtime.h>
#include <hip/hip_fp16.h>

typedef __attribute__((ext_vector_type(4))) float f32x4;
typedef __attribute__((ext_vector_type(2))) unsigned int u32x2;
typedef _Float16 f16x8 __attribute__((ext_vector_type(8)));
typedef _Float16 h2    __attribute__((ext_vector_type(2)));

#define TTOK 10000
#define SBAR() __builtin_amdgcn_sched_barrier(0)

__device__ __forceinline__ h2 pkh(float lo, float hi){
  auto t = __builtin_amdgcn_cvt_pkrtz(lo, hi);   // __fp16 x2 -> bitcast to h2
  union{ decltype(t) a; h2 b; } c; c.a = t; return c.b;
}
__device__ __forceinline__ unsigned h2u(h2 v){ union{h2 h; unsigned u;} c; c.h=v; return c.u; }
__device__ __forceinline__ h2 u2h(unsigned u){ union{unsigned a; h2 b;} c; c.a=u; return c.b; }
__device__ __forceinline__ __half2 h2h(h2 v){ union{h2 a; __half2 b;} c; c.a=v; return c.b; }
__device__ __forceinline__ h2 hh2(__half2 v){ union{__half2 a; h2 b;} c; c.a=v; return c.b; }

__device__ __forceinline__ unsigned short f2h(float f){
  _Float16 h = (_Float16)f;                 // RNE
  union{_Float16 h; unsigned short u;} c; c.h = h; return c.u;
}

// packed-f16 softplus + sigmoid*c accumulate (round 22).
// softplus(x) = (x+|x|)/2 + ln2*log2(1+2^{-|x|*log2e})
// sigmoid(x)  = sign(x)*(rc-0.5)+0.5 where rc = 1/(1+e^{-|x|})  [earc = 1-rc]
__device__ __forceinline__ h2 spsig(h2 ph, h2 cc, h2& dv){
  const h2 nl2e = {(_Float16)(-1.4426950f), (_Float16)(-1.4426950f)};
  const h2 l2   = {(_Float16)(0.6931472f), (_Float16)(0.6931472f)};
  const h2 one  = {(_Float16)1.f, (_Float16)1.f};
  const h2 hlf  = {(_Float16)0.5f, (_Float16)0.5f};
  unsigned pu = h2u(ph);
  h2 ax = u2h(pu & 0x7FFF7FFFu);                     // |x|
  h2 sn = u2h((pu & 0x80008000u) | 0x3C003C00u);     // +-1
  h2 ea  = hh2(h2exp2(h2h(ax*nl2e)));                // e^{-|x|}
  h2 opa = ea + one;
  h2 rc  = hh2(h2rcp(h2h(opa)));
  h2 lg  = hh2(h2log2(h2h(opa)));
  h2 sp  = (ph + ax)*hlf + lg*l2;                    // max(x,0)+log1p
  h2 sg  = sn*(rc - hlf) + hlf;
  dv = sg*cc + dv;
  return sp;
}

// ---------------- prep: fragment-linear f16 weights, hb+t*tw seeds, c ----------------
__global__ void cnf_prep(const float* __restrict__ h, const float* __restrict__ Wx,
                         const float* __restrict__ wxt, const float* __restrict__ bx,
                         const float* __restrict__ Wh, const float* __restrict__ wht,
                         const float* __restrict__ bh, const float* __restrict__ W2,
                         float* __restrict__ hbt, float* __restrict__ cv,
                         unsigned short* __restrict__ wxb, unsigned short* __restrict__ w2b)
{
  const int b = blockIdx.x, t = threadIdx.x;
  if (b < 16) {
    const int jj = b & 7;
    const float* W = (b < 8) ? Wx : W2;
    unsigned short* dst = (b < 8) ? wxb : w2b;
    const int kc = t>>6, l = t&63, q = l&15, g = l>>4;
    #pragma unroll
    for (int i=0;i<8;++i)
      dst[((jj*4+kc)*64 + l)*8 + i] = f2h(W[(jj*16+q)*128 + kc*32 + g*8 + i]);
  } else if (b < 18) {
    for (int i=0;i<4;++i){
      int idx = i*256 + t;
      int sb = (b-16)*8 + (idx>>7);
      int j  = idx & 127;
      float a = 0.f;
      for (int e2=0;e2<128;++e2) a += h[sb*128+e2]*Wh[j*128+e2];
      float base = a + bh[j] + bx[j];
      float tw   = wxt[j] + wht[j];
      for (int ti=0; ti<5; ++ti)
        hbt[(ti*16+sb)*128 + j] = base + 0.25f*(float)ti*tw;   // t in {0,.25,.5,.75,1}
    }
  } else {
    if (t < 128){
      float a = 0.f;
      for (int i=0;i<128;++i) a += W2[i*128+t]*Wx[t*128+i];
      cv[t] = a;
    }
  }
}

// ---------------- fused CNF main kernel ----------------
// Round-22 = round-17/21 champion structure + packed-f16 softplus/sigmoid
// (h2exp2/h2log2/h2rcp, branch-free sign-select, exact packed max via
// (x+|x|)/2), sp emitted pre-packed for the LDS store, c held as packed
// f16 registers, LDS transpose addresses hoisted out of the eval loop.
__global__ __launch_bounds__(256, 2) void cnf_main(
    const float* __restrict__ emb, const float* __restrict__ lp0,
    const float* __restrict__ b2g, const float* __restrict__ hbt,
    const float* __restrict__ cg,  const unsigned short* __restrict__ wxb,
    const unsigned short* __restrict__ w2b, float* __restrict__ out)
{
  __shared__ __align__(16) unsigned short sWx[16384];
  __shared__ __align__(16) unsigned short sW2[16384];
  __shared__ __align__(16) unsigned short sT[4][2048];   // per-tile timeshared z^T/sp^T (4KB)

  const int tid = threadIdx.x;
  const int rowbase = blockIdx.x*64;

  // stage weights into LDS: plain linear copy (layout already fragment-linear)
  for (int it=0; it<8; ++it){
    int L = it*4096 + tid*16;
    *(int4*)((char*)sWx + L) = *(const int4*)((const char*)wxb + L);
    *(int4*)((char*)sW2 + L) = *(const int4*)((const char*)w2b + L);
  }
  __syncthreads();

  const int w = tid>>6, tg = w>>1, hw = w&1, l = tid&63, q = l&15, g = l>>4;
  char* zB0 = (char*)&sT[2*tg][0];
  char* zB1 = (char*)&sT[2*tg+1][0];
  const char* wxBase = (const char*)sWx + hw*16384 + l*16;  // + (j*4+kc)*1024 imm
  const char* w2Base = (const char*)sW2 + hw*16384 + l*16;
  const int cwB = q*16 + 8*(g&1) + 256*(g>>1);
  const int crB = g*256 + q*16;
  const int hof = hw*64 + 4*g;                  // h/e base for this wave: + 16*j + r

  // loop-invariant swizzled LDS addresses
  int wadr[4], radr[4];
  #pragma unroll
  for (int j=0; j<4; ++j){ int W = (hw*4+j)*512 + cwB; W ^= ((W>>8)&7)<<4; wadr[j] = W; }
  #pragma unroll
  for (int kc=0; kc<4; ++kc){ int R = kc*1024 + crB; R ^= ((R>>8)&7)<<4; radr[kc] = R; }

  const int row0 = rowbase + tg*32 + q;
  const int row1 = row0 + 16;
  const int sb0 = row0/TTOK, tt0 = row0 - sb0*TTOK;
  const int sb1 = row1/TTOK, tt1 = row1 - sb1*TTOK;

  h2 zbp0[4][2], zbp1[4][2];   // z state, packed f16 (16 VGPRs)
  h2 ksp0[4][2], ksp1[4][2];   // RK4 running sum, packed f16 (16 VGPRs)
  f32x4 wk0[4], wk1[4];        // f32 accumulators
  f32x4 b2r[4];                // persistent b2 (f32 seeds)
  h2 ccp[4][2];                // persistent c, packed f16 (8 VGPRs)
  h2 dlt20 = (h2){0,0}, dlt21 = (h2){0,0};

  #pragma unroll
  for (int j=0; j<4; ++j){
    f32x4 e0 = *(const f32x4*)(emb + tt0*128 + hof + 16*j);
    f32x4 e1 = *(const f32x4*)(emb + tt1*128 + hof + 16*j);
    zbp0[j][0] = pkh(e0[0], e0[1]);
    zbp0[j][1] = pkh(e0[2], e0[3]);
    zbp1[j][0] = pkh(e1[0], e1[1]);
    zbp1[j][1] = pkh(e1[2], e1[3]);
    wk0[j] = (f32x4){0.f,0.f,0.f,0.f};
    wk1[j] = (f32x4){0.f,0.f,0.f,0.f};
    ksp0[j][0] = (h2){0,0}; ksp0[j][1] = (h2){0,0};
    ksp1[j][0] = (h2){0,0}; ksp1[j][1] = (h2){0,0};
    b2r[j] = *(const f32x4*)(b2g + hof + 16*j);
    f32x4 c4 = *(const f32x4*)(cg + hof + 16*j);
    ccp[j][0] = pkh(c4[0], c4[1]);
    ccp[j][1] = pkh(c4[2], c4[3]);
  }

  #pragma unroll 1
  for (int se=0; se<8; ++se){
    const int   s    = se>>2, e = se&3;
    const float coef = (e==0)?0.f:((e==3)?0.5f:0.25f); // z_eval = z_base + coef*k_prev
    const float we   = (e==1||e==2)?2.f:1.f;
    const int   ti   = 2*s + ((e==0)?0:((e<3)?1:2));
    const _Float16 ch = (_Float16)coef;
    const h2 coef2 = {ch, ch};
    const _Float16 wh_ = (_Float16)we;
    const h2 we2 = {wh_, wh_};
    const h2 c12 = {(_Float16)(1.f/12.f), (_Float16)(1.f/12.f)};

    // ---- phase 1: prefetch hb seeds; pack z_eval (both tiles) -> z^T buffers
    f32x4 hb0[4], hb1[4];
    {
      const float* p0 = hbt + (ti*16 + sb0)*128 + hof;
      const float* p1 = hbt + (ti*16 + sb1)*128 + hof;
      #pragma unroll
      for (int j=0; j<4; ++j){
        hb0[j] = *(const f32x4*)(p0 + 16*j);
        hb1[j] = *(const f32x4*)(p1 + 16*j);
      }
    }
    #pragma unroll
    for (int j=0; j<4; ++j){
      u32x2 wv0, wv1;
      if (e==0){
        wv0[0] = h2u(zbp0[j][0]); wv0[1] = h2u(zbp0[j][1]);
        wv1[0] = h2u(zbp1[j][0]); wv1[1] = h2u(zbp1[j][1]);
      } else {
        h2 a0 = pkh(wk0[j][0], wk0[j][1]);
        h2 a1 = pkh(wk0[j][2], wk0[j][3]);
        h2 z0 = coef2*a0 + zbp0[j][0];
        h2 z1 = coef2*a1 + zbp0[j][1];
        wv0[0] = h2u(z0); wv0[1] = h2u(z1);
        h2 b0 = pkh(wk1[j][0], wk1[j][1]);
        h2 b1 = pkh(wk1[j][2], wk1[j][3]);
        h2 y0 = coef2*b0 + zbp1[j][0];
        h2 y1 = coef2*b1 + zbp1[j][1];
        wv1[0] = h2u(y0); wv1[1] = h2u(y1);
      }
      *(u32x2*)(zB0 + wadr[j]) = wv0;
      *(u32x2*)(zB1 + wadr[j]) = wv1;
    }
    SBAR();
    __syncthreads();   // z^T complete (both halves, both tiles)

    // ---- phase 3: matmul1 (h-half, both tiles): seed = prefetched hb
    #pragma unroll
    for (int j=0; j<4; ++j){ wk0[j] = hb0[j]; wk1[j] = hb1[j]; }
    __builtin_amdgcn_s_setprio(1);
    #pragma unroll
    for (int kc=0; kc<4; ++kc){
      f16x8 zf0 = *(const f16x8*)(zB0 + radr[kc]);
      f16x8 zf1 = *(const f16x8*)(zB1 + radr[kc]);
      #pragma unroll
      for (int j=0; j<4; ++j){
        f16x8 af = *(const f16x8*)(wxBase + (j*4+kc)*1024);
        wk0[j] = __builtin_amdgcn_mfma_f32_16x16x32_f16(af, zf0, wk0[j], 0,0,0);
        wk1[j] = __builtin_amdgcn_mfma_f32_16x16x32_f16(af, zf1, wk1[j], 0,0,0);
      }
      SBAR();
    }
    __builtin_amdgcn_s_setprio(0);
    __syncthreads();   // z^T reads done; buffers free for sp^T

    // ---- phase 4: packed-f16 softplus both tiles -> sp^T buffers, sigmoid*c -> div
    h2 dv20 = (h2){0,0}, dv21 = (h2){0,0};
    #pragma unroll
    for (int j=0; j<4; ++j){
      h2 p00 = pkh(wk0[j][0], wk0[j][1]);
      h2 p01 = pkh(wk0[j][2], wk0[j][3]);
      h2 s00 = spsig(p00, ccp[j][0], dv20);
      h2 s01 = spsig(p01, ccp[j][1], dv20);
      h2 p10 = pkh(wk1[j][0], wk1[j][1]);
      h2 p11 = pkh(wk1[j][2], wk1[j][3]);
      h2 s10 = spsig(p10, ccp[j][0], dv21);
      h2 s11 = spsig(p11, ccp[j][1], dv21);
      u32x2 wv0 = { h2u(s00), h2u(s01) };
      u32x2 wv1 = { h2u(s10), h2u(s11) };
      *(u32x2*)(zB0 + wadr[j]) = wv0;
      *(u32x2*)(zB1 + wadr[j]) = wv1;
    }
    dlt20 = we2*dv20 + dlt20;
    dlt21 = we2*dv21 + dlt21;
    SBAR();
    __syncthreads();   // sp^T complete

    // ---- phase 5: matmul2 (o-half, both tiles): seed = persistent b2
    #pragma unroll
    for (int j=0; j<4; ++j){ wk0[j] = b2r[j]; wk1[j] = b2r[j]; }
    __builtin_amdgcn_s_setprio(1);
    #pragma unroll
    for (int kc=0; kc<4; ++kc){
      f16x8 sf0 = *(const f16x8*)(zB0 + radr[kc]);
      f16x8 sf1 = *(const f16x8*)(zB1 + radr[kc]);
      #pragma unroll
      for (int j=0; j<4; ++j){
        f16x8 af = *(const f16x8*)(w2Base + (j*4+kc)*1024);
        wk0[j] = __builtin_amdgcn_mfma_f32_16x16x32_f16(af, sf0, wk0[j], 0,0,0);
        wk1[j] = __builtin_amdgcn_mfma_f32_16x16x32_f16(af, sf1, wk1[j], 0,0,0);
      }
      SBAR();
    }
    __builtin_amdgcn_s_setprio(0);

    // ---- phase 6: RK4 accumulate (both tiles; wk = k_e), packed f16
    if (e==0){
      #pragma unroll
      for (int j=0;j<4;++j){
        ksp0[j][0] = pkh(wk0[j][0], wk0[j][1]);
        ksp0[j][1] = pkh(wk0[j][2], wk0[j][3]);
        ksp1[j][0] = pkh(wk1[j][0], wk1[j][1]);
        ksp1[j][1] = pkh(wk1[j][2], wk1[j][3]);
      }
    } else if (e<3){
      #pragma unroll
      for (int j=0;j<4;++j){
        ksp0[j][0] = we2*pkh(wk0[j][0], wk0[j][1]) + ksp0[j][0];
        ksp0[j][1] = we2*pkh(wk0[j][2], wk0[j][3]) + ksp0[j][1];
        ksp1[j][0] = we2*pkh(wk1[j][0], wk1[j][1]) + ksp1[j][0];
        ksp1[j][1] = we2*pkh(wk1[j][2], wk1[j][3]) + ksp1[j][1];
      }
    } else {
      #pragma unroll
      for (int j=0;j<4;++j){
        h2 t00 = ksp0[j][0] + pkh(wk0[j][0], wk0[j][1]);
        h2 t01 = ksp0[j][1] + pkh(wk0[j][2], wk0[j][3]);
        zbp0[j][0] = c12*t00 + zbp0[j][0];
        zbp0[j][1] = c12*t01 + zbp0[j][1];
        h2 t10 = ksp1[j][0] + pkh(wk1[j][0], wk1[j][1]);
        h2 t11 = ksp1[j][1] + pkh(wk1[j][2], wk1[j][3]);
        zbp1[j][0] = c12*t10 + zbp1[j][0];
        zbp1[j][1] = c12*t11 + zbp1[j][1];
      }
    }
    SBAR();
    __syncthreads();   // sp^T reads done; buffers free for next eval's z^T
  }

  // ---- epilogue: g-reduce div partials, cross-wave combine via LDS (reuse zB0)
  {
    float d0 = (float)dlt20[0] + (float)dlt20[1];
    float d1 = (float)dlt21[0] + (float)dlt21[1];
    d0 += __shfl_xor(d0, 16, 64);
    d0 += __shfl_xor(d0, 32, 64);
    d1 += __shfl_xor(d1, 16, 64);
    d1 += __shfl_xor(d1, 32, 64);
    float* fDv = (float*)zB0;
    if (g==0){
      fDv[hw*16 + q]      = d0;
      fDv[32 + hw*16 + q] = d1;
    }
    __syncthreads();
    if (hw==0 && g==0){
      float t0 = (fDv[q] + fDv[16+q]) * (1.f/12.f);
      float t1 = (fDv[32+q] + fDv[48+q]) * (1.f/12.f);
      out[row0] = lp0[row0] - t0;
      out[row1] = lp0[row1] - t1;
    }
  }
}

extern "C" void kernel_launch(void* const* d_in, const int* in_sizes, int n_in,
                              void* d_out, int out_size, void* d_ws, size_t ws_size,
                              hipStream_t stream) {
  const float* h    = (const float*)d_in[0];
  const float* emb  = (const float*)d_in[1];
  const float* lp0  = (const float*)d_in[2];
  const float* Wx   = (const float*)d_in[3];
  const float* wxt  = (const float*)d_in[4];
  const float* bx   = (const float*)d_in[5];
  const float* Wh   = (const float*)d_in[6];
  const float* wht  = (const float*)d_in[7];
  const float* bh   = (const float*)d_in[8];
  const float* W2   = (const float*)d_in[9];
  const float* b2   = (const float*)d_in[10];
  float* out = (float*)d_out;

  char* ws = (char*)d_ws;
  float* hbt          = (float*)ws;            // 5*16*128 f32 = 40960 B
  float* cv           = (float*)(ws + 40960);  // 128 f32     = 512 B
  unsigned short* wxb = (unsigned short*)(ws + 41472); // 16384 f16 = 32768 B
  unsigned short* w2b = (unsigned short*)(ws + 74240); // 16384 f16 = 32768 B

  cnf_prep<<<19, 256, 0, stream>>>(h, Wx, wxt, bx, Wh, wht, bh, W2, hbt, cv, wxb, w2b);
  cnf_main<<<2500, 256, 0, stream>>>(emb, lp0, b2, hbt, cv, wxb, w2b, out);
}

// Round 23
// 147.198 us; speedup vs baseline: 4.4585x; 1.0974x over previous
//
#include <hip/hip_runtime.h>
#include <hip/hip_fp16.h>

typedef __attribute__((ext_vector_type(4))) float f32x4;
typedef _Float16 h2 __attribute__((ext_vector_type(2)));

#define TTOK 10000
#define SBAR() __builtin_amdgcn_sched_barrier(0)

__device__ __forceinline__ h2 pkh(float lo, float hi){
  auto t = __builtin_amdgcn_cvt_pkrtz(lo, hi);
  union{ decltype(t) a; h2 b; } c; c.a = t; return c.b;
}
__device__ __forceinline__ unsigned h2u(h2 v){ union{h2 h; unsigned u;} c; c.h=v; return c.u; }
__device__ __forceinline__ h2 u2h(unsigned u){ union{unsigned a; h2 b;} c; c.a=u; return c.b; }
__device__ __forceinline__ __half2 h2h(h2 v){ union{h2 a; __half2 b;} c; c.a=v; return c.b; }
__device__ __forceinline__ h2 hh2(__half2 v){ union{__half2 a; h2 b;} c; c.a=v; return c.b; }

__device__ __forceinline__ unsigned short f2h(float f){
  _Float16 h = (_Float16)f;
  union{_Float16 h; unsigned short u;} c; c.h = h; return c.u;
}

// packed-f16 softplus + sigmoid*c accumulate (round 22, verified).
__device__ __forceinline__ h2 spsig(h2 ph, h2 cc, h2& dv){
  const h2 nl2e = {(_Float16)(-1.4426950f), (_Float16)(-1.4426950f)};
  const h2 l2   = {(_Float16)(0.6931472f), (_Float16)(0.6931472f)};
  const h2 one  = {(_Float16)1.f, (_Float16)1.f};
  const h2 hlf  = {(_Float16)0.5f, (_Float16)0.5f};
  unsigned pu = h2u(ph);
  h2 ax = u2h(pu & 0x7FFF7FFFu);
  h2 sn = u2h((pu & 0x80008000u) | 0x3C003C00u);
  h2 ea  = hh2(h2exp2(h2h(ax*nl2e)));
  h2 opa = ea + one;
  h2 rc  = hh2(h2rcp(h2h(opa)));
  h2 lg  = hh2(h2log2(h2h(opa)));
  h2 sp  = (ph + ax)*hlf + lg*l2;
  h2 sg  = sn*(rc - hlf) + hlf;
  dv = sg*cc + dv;
  return sp;
}

// ---------------- prep: fragment-linear FP8 (e4m3) weights, hb seeds, c ----------------
// wb[((jj*4+kc)*64 + l)*8 + i] = fp8(W[jj*16+q][kc*32+g*8+i]), l=g*16+q.
// A-fragment for mfma_16x16x32_fp8_fp8: lane holds 8 consecutive k as 8 bytes
// (same index structure as f16, 1B/elem). Wave frag read = 512B linear.
__global__ void cnf_prep(const float* __restrict__ h, const float* __restrict__ Wx,
                         const float* __restrict__ wxt, const float* __restrict__ bx,
                         const float* __restrict__ Wh, const float* __restrict__ wht,
                         const float* __restrict__ bh, const float* __restrict__ W2,
                         float* __restrict__ hbt, float* __restrict__ cv,
                         unsigned char* __restrict__ wxb, unsigned char* __restrict__ w2b)
{
  const int b = blockIdx.x, t = threadIdx.x;
  if (b < 16) {
    const int jj = b & 7;
    const float* W = (b < 8) ? Wx : W2;
    unsigned char* dst = (b < 8) ? wxb : w2b;
    const int kc = t>>6, l = t&63, q = l&15, g = l>>4;
    #pragma unroll
    for (int i=0;i<8;++i){
      float wv = W[(jj*16+q)*128 + kc*32 + g*8 + i];
      unsigned pkv = __builtin_amdgcn_cvt_pk_fp8_f32(wv, wv, 0, false);
      dst[((jj*4+kc)*64 + l)*8 + i] = (unsigned char)(pkv & 0xFF);
    }
  } else if (b < 18) {
    for (int i=0;i<4;++i){
      int idx = i*256 + t;
      int sb = (b-16)*8 + (idx>>7);
      int j  = idx & 127;
      float a = 0.f;
      for (int e2=0;e2<128;++e2) a += h[sb*128+e2]*Wh[j*128+e2];
      float base = a + bh[j] + bx[j];
      float tw   = wxt[j] + wht[j];
      for (int ti=0; ti<5; ++ti)
        hbt[(ti*16+sb)*128 + j] = base + 0.25f*(float)ti*tw;   // t in {0,.25,.5,.75,1}
    }
  } else {
    if (t < 128){
      float a = 0.f;
      for (int i=0;i<128;++i) a += W2[i*128+t]*Wx[t*128+i];
      cv[t] = a;
    }
  }
}

// ---------------- fused CNF main kernel ----------------
// Round-23 = round-22 structure with FP8 (e4m3) MFMA datapath. z/ks state
// and softplus stay packed f16; weights + transposed activations are fp8.
// LDS: 16KB Wx + 16KB W2 + 4x2KB buffers = 40KB -> 3-4 blocks/CU (breaks
// the 80KB/2-block cap that pinned rounds 10-22 at 2 waves/SIMD). fp8
// buffer layout is fully linear (write 2-way free, read conflict-free, no
// swizzle). (256,3): r16 precedent, no spill at ~95-reg demand.
__global__ __launch_bounds__(256, 3) void cnf_main(
    const float* __restrict__ emb, const float* __restrict__ lp0,
    const float* __restrict__ b2g, const float* __restrict__ hbt,
    const float* __restrict__ cg,  const unsigned char* __restrict__ wxb,
    const unsigned char* __restrict__ w2b, float* __restrict__ out)
{
  __shared__ __align__(16) unsigned char sWx[16384];
  __shared__ __align__(16) unsigned char sW2[16384];
  __shared__ __align__(16) unsigned char sT[4][2048];   // per-tile timeshared z^T/sp^T (2KB, fp8)

  const int tid = threadIdx.x;
  const int rowbase = blockIdx.x*64;

  // stage fp8 weights into LDS: plain linear copy
  for (int it=0; it<4; ++it){
    int L = it*4096 + tid*16;
    *(int4*)(sWx + L) = *(const int4*)(wxb + L);
    *(int4*)(sW2 + L) = *(const int4*)(w2b + L);
  }
  __syncthreads();

  const int w = tid>>6, tg = w>>1, hw = w&1, l = tid&63, q = l&15, g = l>>4;
  unsigned char* zB0 = &sT[2*tg][0];
  unsigned char* zB1 = &sT[2*tg+1][0];
  const unsigned char* wxBase = sWx + hw*8192 + l*8;   // + (j*4+kc)*512 imm
  const unsigned char* w2Base = sW2 + hw*8192 + l*8;
  const int hof = hw*64 + 4*g;                  // h/e base for this wave: + 16*j + r

  // loop-invariant LDS addresses (fp8 layout: no swizzle needed)
  int wadr[4], radr[4];
  #pragma unroll
  for (int j=0; j<4; ++j) wadr[j] = (hw*4+j)*256 + q*8 + 4*(g&1) + 128*(g>>1);
  #pragma unroll
  for (int kc=0; kc<4; ++kc) radr[kc] = kc*512 + g*128 + q*8;

  const int row0 = rowbase + tg*32 + q;
  const int row1 = row0 + 16;
  const int sb0 = row0/TTOK, tt0 = row0 - sb0*TTOK;
  const int sb1 = row1/TTOK, tt1 = row1 - sb1*TTOK;

  h2 zbp0[4][2], zbp1[4][2];   // z state, packed f16 (16 VGPRs)
  h2 ksp0[4][2], ksp1[4][2];   // RK4 running sum, packed f16 (16 VGPRs)
  f32x4 wk0[4], wk1[4];        // f32 accumulators
  f32x4 b2r[4];                // persistent b2 (f32 seeds)
  h2 ccp[4][2];                // persistent c, packed f16
  h2 dlt20 = (h2){0,0}, dlt21 = (h2){0,0};

  #pragma unroll
  for (int j=0; j<4; ++j){
    f32x4 e0 = *(const f32x4*)(emb + tt0*128 + hof + 16*j);
    f32x4 e1 = *(const f32x4*)(emb + tt1*128 + hof + 16*j);
    zbp0[j][0] = pkh(e0[0], e0[1]);
    zbp0[j][1] = pkh(e0[2], e0[3]);
    zbp1[j][0] = pkh(e1[0], e1[1]);
    zbp1[j][1] = pkh(e1[2], e1[3]);
    wk0[j] = (f32x4){0.f,0.f,0.f,0.f};
    wk1[j] = (f32x4){0.f,0.f,0.f,0.f};
    ksp0[j][0] = (h2){0,0}; ksp0[j][1] = (h2){0,0};
    ksp1[j][0] = (h2){0,0}; ksp1[j][1] = (h2){0,0};
    b2r[j] = *(const f32x4*)(b2g + hof + 16*j);
    f32x4 c4 = *(const f32x4*)(cg + hof + 16*j);
    ccp[j][0] = pkh(c4[0], c4[1]);
    ccp[j][1] = pkh(c4[2], c4[3]);
  }

  #pragma unroll 1
  for (int se=0; se<8; ++se){
    const int   s    = se>>2, e = se&3;
    const float coef = (e==0)?0.f:((e==3)?0.5f:0.25f); // z_eval = z_base + coef*k_prev
    const float we   = (e==1||e==2)?2.f:1.f;
    const int   ti   = 2*s + ((e==0)?0:((e<3)?1:2));
    const _Float16 wh_ = (_Float16)we;
    const h2 we2 = {wh_, wh_};
    const h2 c12 = {(_Float16)(1.f/12.f), (_Float16)(1.f/12.f)};

    // ---- phase 1: prefetch hb seeds; z_eval = coef*k + z (f32), cvt->fp8 -> z^T
    // (unified path: coef=0 at e==0 reproduces z exactly)
    f32x4 hb0[4], hb1[4];
    {
      const float* p0 = hbt + (ti*16 + sb0)*128 + hof;
      const float* p1 = hbt + (ti*16 + sb1)*128 + hof;
      #pragma unroll
      for (int j=0; j<4; ++j){
        hb0[j] = *(const f32x4*)(p0 + 16*j);
        hb1[j] = *(const f32x4*)(p1 + 16*j);
      }
    }
    #pragma unroll
    for (int j=0; j<4; ++j){
      float v0 = fmaf(coef, wk0[j][0], (float)zbp0[j][0][0]);
      float v1 = fmaf(coef, wk0[j][1], (float)zbp0[j][0][1]);
      float v2 = fmaf(coef, wk0[j][2], (float)zbp0[j][1][0]);
      float v3 = fmaf(coef, wk0[j][3], (float)zbp0[j][1][1]);
      int p0 = __builtin_amdgcn_cvt_pk_fp8_f32(v0, v1, 0, false);
      p0 = __builtin_amdgcn_cvt_pk_fp8_f32(v2, v3, p0, true);
      *(int*)(zB0 + wadr[j]) = p0;
      float y0 = fmaf(coef, wk1[j][0], (float)zbp1[j][0][0]);
      float y1 = fmaf(coef, wk1[j][1], (float)zbp1[j][0][1]);
      float y2 = fmaf(coef, wk1[j][2], (float)zbp1[j][1][0]);
      float y3 = fmaf(coef, wk1[j][3], (float)zbp1[j][1][1]);
      int p1v = __builtin_amdgcn_cvt_pk_fp8_f32(y0, y1, 0, false);
      p1v = __builtin_amdgcn_cvt_pk_fp8_f32(y2, y3, p1v, true);
      *(int*)(zB1 + wadr[j]) = p1v;
    }
    SBAR();
    __syncthreads();   // z^T complete (both halves, both tiles)

    // ---- phase 2: matmul1 (h-half, both tiles), fp8 MFMA: seed = prefetched hb
    #pragma unroll
    for (int j=0; j<4; ++j){ wk0[j] = hb0[j]; wk1[j] = hb1[j]; }
    __builtin_amdgcn_s_setprio(1);
    #pragma unroll
    for (int kc=0; kc<4; ++kc){
      long zf0 = *(const long*)(zB0 + radr[kc]);
      long zf1 = *(const long*)(zB1 + radr[kc]);
      #pragma unroll
      for (int j=0; j<4; ++j){
        long af = *(const long*)(wxBase + (j*4+kc)*512);
        wk0[j] = __builtin_amdgcn_mfma_f32_16x16x32_fp8_fp8(af, zf0, wk0[j], 0,0,0);
        wk1[j] = __builtin_amdgcn_mfma_f32_16x16x32_fp8_fp8(af, zf1, wk1[j], 0,0,0);
      }
      SBAR();
    }
    __builtin_amdgcn_s_setprio(0);
    __syncthreads();   // z^T reads done; buffers free for sp^T

    // ---- phase 3: packed-f16 softplus -> fp8 sp^T, sigmoid*c -> div
    h2 dv20 = (h2){0,0}, dv21 = (h2){0,0};
    #pragma unroll
    for (int j=0; j<4; ++j){
      h2 p00 = pkh(wk0[j][0], wk0[j][1]);
      h2 p01 = pkh(wk0[j][2], wk0[j][3]);
      h2 s00 = spsig(p00, ccp[j][0], dv20);
      h2 s01 = spsig(p01, ccp[j][1], dv20);
      int q0 = __builtin_amdgcn_cvt_pk_fp8_f32((float)s00[0], (float)s00[1], 0, false);
      q0 = __builtin_amdgcn_cvt_pk_fp8_f32((float)s01[0], (float)s01[1], q0, true);
      *(int*)(zB0 + wadr[j]) = q0;
      h2 p10 = pkh(wk1[j][0], wk1[j][1]);
      h2 p11 = pkh(wk1[j][2], wk1[j][3]);
      h2 s10 = spsig(p10, ccp[j][0], dv21);
      h2 s11 = spsig(p11, ccp[j][1], dv21);
      int q1 = __builtin_amdgcn_cvt_pk_fp8_f32((float)s10[0], (float)s10[1], 0, false);
      q1 = __builtin_amdgcn_cvt_pk_fp8_f32((float)s11[0], (float)s11[1], q1, true);
      *(int*)(zB1 + wadr[j]) = q1;
    }
    dlt20 = we2*dv20 + dlt20;
    dlt21 = we2*dv21 + dlt21;
    SBAR();
    __syncthreads();   // sp^T complete

    // ---- phase 4: matmul2 (o-half, both tiles), fp8 MFMA: seed = persistent b2
    #pragma unroll
    for (int j=0; j<4; ++j){ wk0[j] = b2r[j]; wk1[j] = b2r[j]; }
    __builtin_amdgcn_s_setprio(1);
    #pragma unroll
    for (int kc=0; kc<4; ++kc){
      long sf0 = *(const long*)(zB0 + radr[kc]);
      long sf1 = *(const long*)(zB1 + radr[kc]);
      #pragma unroll
      for (int j=0; j<4; ++j){
        long af = *(const long*)(w2Base + (j*4+kc)*512);
        wk0[j] = __builtin_amdgcn_mfma_f32_16x16x32_fp8_fp8(af, sf0, wk0[j], 0,0,0);
        wk1[j] = __builtin_amdgcn_mfma_f32_16x16x32_fp8_fp8(af, sf1, wk1[j], 0,0,0);
      }
      SBAR();
    }
    __builtin_amdgcn_s_setprio(0);

    // ---- phase 5: RK4 accumulate (both tiles; wk = k_e), packed f16
    if (e==0){
      #pragma unroll
      for (int j=0;j<4;++j){
        ksp0[j][0] = pkh(wk0[j][0], wk0[j][1]);
        ksp0[j][1] = pkh(wk0[j][2], wk0[j][3]);
        ksp1[j][0] = pkh(wk1[j][0], wk1[j][1]);
        ksp1[j][1] = pkh(wk1[j][2], wk1[j][3]);
      }
    } else if (e<3){
      #pragma unroll
      for (int j=0;j<4;++j){
        ksp0[j][0] = we2*pkh(wk0[j][0], wk0[j][1]) + ksp0[j][0];
        ksp0[j][1] = we2*pkh(wk0[j][2], wk0[j][3]) + ksp0[j][1];
        ksp1[j][0] = we2*pkh(wk1[j][0], wk1[j][1]) + ksp1[j][0];
        ksp1[j][1] = we2*pkh(wk1[j][2], wk1[j][3]) + ksp1[j][1];
      }
    } else {
      #pragma unroll
      for (int j=0;j<4;++j){
        h2 t00 = ksp0[j][0] + pkh(wk0[j][0], wk0[j][1]);
        h2 t01 = ksp0[j][1] + pkh(wk0[j][2], wk0[j][3]);
        zbp0[j][0] = c12*t00 + zbp0[j][0];
        zbp0[j][1] = c12*t01 + zbp0[j][1];
        h2 t10 = ksp1[j][0] + pkh(wk1[j][0], wk1[j][1]);
        h2 t11 = ksp1[j][1] + pkh(wk1[j][2], wk1[j][3]);
        zbp1[j][0] = c12*t10 + zbp1[j][0];
        zbp1[j][1] = c12*t11 + zbp1[j][1];
      }
    }
    SBAR();
    __syncthreads();   // sp^T reads done; buffers free for next eval's z^T
  }

  // ---- epilogue: g-reduce div partials, cross-wave combine via LDS (reuse zB0)
  {
    float d0 = (float)dlt20[0] + (float)dlt20[1];
    float d1 = (float)dlt21[0] + (float)dlt21[1];
    d0 += __shfl_xor(d0, 16, 64);
    d0 += __shfl_xor(d0, 32, 64);
    d1 += __shfl_xor(d1, 16, 64);
    d1 += __shfl_xor(d1, 32, 64);
    float* fDv = (float*)zB0;
    if (g==0){
      fDv[hw*16 + q]      = d0;
      fDv[32 + hw*16 + q] = d1;
    }
    __syncthreads();
    if (hw==0 && g==0){
      float t0 = (fDv[q] + fDv[16+q]) * (1.f/12.f);
      float t1 = (fDv[32+q] + fDv[48+q]) * (1.f/12.f);
      out[row0] = lp0[row0] - t0;
      out[row1] = lp0[row1] - t1;
    }
  }
}

extern "C" void kernel_launch(void* const* d_in, const int* in_sizes, int n_in,
                              void* d_out, int out_size, void* d_ws, size_t ws_size,
                              hipStream_t stream) {
  const float* h    = (const float*)d_in[0];
  const float* emb  = (const float*)d_in[1];
  const float* lp0  = (const float*)d_in[2];
  const float* Wx   = (const float*)d_in[3];
  const float* wxt  = (const float*)d_in[4];
  const float* bx   = (const float*)d_in[5];
  const float* Wh   = (const float*)d_in[6];
  const float* wht  = (const float*)d_in[7];
  const float* bh   = (const float*)d_in[8];
  const float* W2   = (const float*)d_in[9];
  const float* b2   = (const float*)d_in[10];
  float* out = (float*)d_out;

  char* ws = (char*)d_ws;
  float* hbt          = (float*)ws;                    // 5*16*128 f32 = 40960 B
  float* cv           = (float*)(ws + 40960);          // 128 f32     = 512 B
  unsigned char* wxb  = (unsigned char*)(ws + 41472);  // 16384 fp8   = 16384 B
  unsigned char* w2b  = (unsigned char*)(ws + 57856);  // 16384 fp8   = 16384 B

  cnf_prep<<<19, 256, 0, stream>>>(h, Wx, wxt, bx, Wh, wht, bh, W2, hbt, cv, wxb, w2b);
  cnf_main<<<2500, 256, 0, stream>>>(emb, lp0, b2, hbt, cv, wxb, w2b, out);
}

// Round 24
// 143.985 us; speedup vs baseline: 4.5580x; 1.0223x over previous
//
#include <hip/hip_runtime.h>
#include <hip/hip_fp16.h>

typedef __attribute__((ext_vector_type(4))) float f32x4;
typedef _Float16 h2 __attribute__((ext_vector_type(2)));

#define TTOK 10000
#define SBAR() __builtin_amdgcn_sched_barrier(0)

__device__ __forceinline__ h2 pkh(float lo, float hi){
  auto t = __builtin_amdgcn_cvt_pkrtz(lo, hi);
  union{ decltype(t) a; h2 b; } c; c.a = t; return c.b;
}
__device__ __forceinline__ unsigned h2u(h2 v){ union{h2 h; unsigned u;} c; c.h=v; return c.u; }
__device__ __forceinline__ h2 u2h(unsigned u){ union{unsigned a; h2 b;} c; c.a=u; return c.b; }
__device__ __forceinline__ __half2 h2h(h2 v){ union{h2 a; __half2 b;} c; c.a=v; return c.b; }
__device__ __forceinline__ h2 hh2(__half2 v){ union{__half2 a; h2 b;} c; c.a=v; return c.b; }

__device__ __forceinline__ unsigned short f2h(float f){
  _Float16 h = (_Float16)f;
  union{_Float16 h; unsigned short u;} c; c.h = h; return c.u;
}

// gfx950 packed f16 -> fp8(e4m3) convert, scale = 1.0 (identity).
// Two partial 16-bit dst writes assemble 4 fp8 bytes in one dword.
__device__ __forceinline__ int pk2fp8(h2 lo, h2 hi){
  int d = 0;
  asm("v_cvt_scalef32_pk_fp8_f16 %0, %1, 1.0" : "+v"(d) : "v"(lo));
  asm("v_cvt_scalef32_pk_fp8_f16 %0, %1, 1.0 op_sel:[0,0,1]" : "+v"(d) : "v"(hi));
  return d;
}

// packed-f16 softplus + sigmoid*c accumulate (round 22, verified).
__device__ __forceinline__ h2 spsig(h2 ph, h2 cc, h2& dv){
  const h2 nl2e = {(_Float16)(-1.4426950f), (_Float16)(-1.4426950f)};
  const h2 l2   = {(_Float16)(0.6931472f), (_Float16)(0.6931472f)};
  const h2 one  = {(_Float16)1.f, (_Float16)1.f};
  const h2 hlf  = {(_Float16)0.5f, (_Float16)0.5f};
  unsigned pu = h2u(ph);
  h2 ax = u2h(pu & 0x7FFF7FFFu);
  h2 sn = u2h((pu & 0x80008000u) | 0x3C003C00u);
  h2 ea  = hh2(h2exp2(h2h(ax*nl2e)));
  h2 opa = ea + one;
  h2 rc  = hh2(h2rcp(h2h(opa)));
  h2 lg  = hh2(h2log2(h2h(opa)));
  h2 sp  = (ph + ax)*hlf + lg*l2;
  h2 sg  = sn*(rc - hlf) + hlf;
  dv = sg*cc + dv;
  return sp;
}

// ---------------- prep: fragment-linear FP8 (e4m3) weights, hb seeds, c ----------------
__global__ void cnf_prep(const float* __restrict__ h, const float* __restrict__ Wx,
                         const float* __restrict__ wxt, const float* __restrict__ bx,
                         const float* __restrict__ Wh, const float* __restrict__ wht,
                         const float* __restrict__ bh, const float* __restrict__ W2,
                         float* __restrict__ hbt, float* __restrict__ cv,
                         unsigned char* __restrict__ wxb, unsigned char* __restrict__ w2b)
{
  const int b = blockIdx.x, t = threadIdx.x;
  if (b < 16) {
    const int jj = b & 7;
    const float* W = (b < 8) ? Wx : W2;
    unsigned char* dst = (b < 8) ? wxb : w2b;
    const int kc = t>>6, l = t&63, q = l&15, g = l>>4;
    #pragma unroll
    for (int i=0;i<8;++i){
      float wv = W[(jj*16+q)*128 + kc*32 + g*8 + i];
      unsigned pkv = __builtin_amdgcn_cvt_pk_fp8_f32(wv, wv, 0, false);
      dst[((jj*4+kc)*64 + l)*8 + i] = (unsigned char)(pkv & 0xFF);
    }
  } else if (b < 18) {
    for (int i=0;i<4;++i){
      int idx = i*256 + t;
      int sb = (b-16)*8 + (idx>>7);
      int j  = idx & 127;
      float a = 0.f;
      for (int e2=0;e2<128;++e2) a += h[sb*128+e2]*Wh[j*128+e2];
      float base = a + bh[j] + bx[j];
      float tw   = wxt[j] + wht[j];
      for (int ti=0; ti<5; ++ti)
        hbt[(ti*16+sb)*128 + j] = base + 0.25f*(float)ti*tw;   // t in {0,.25,.5,.75,1}
    }
  } else {
    if (t < 128){
      float a = 0.f;
      for (int i=0;i<128;++i) a += W2[i*128+t]*Wx[t*128+i];
      cv[t] = a;
    }
  }
}

// ---------------- fused CNF main kernel ----------------
// Round-24 = round-23 fp8 structure + f16->fp8 packed converts
// (v_cvt_scalef32_pk_fp8_f16): phase-1 z_eval stays in packed f16
// (2 pk_fma) and converts h2->fp8 directly; phase-3 softplus output
// converts h2->fp8 directly. Cuts ~64 VALU ops/eval/thread from the
// 75%-busy VALU pipe. LDS 40KB -> ~3 blocks/CU (r23).
__global__ __launch_bounds__(256, 3) void cnf_main(
    const float* __restrict__ emb, const float* __restrict__ lp0,
    const float* __restrict__ b2g, const float* __restrict__ hbt,
    const float* __restrict__ cg,  const unsigned char* __restrict__ wxb,
    const unsigned char* __restrict__ w2b, float* __restrict__ out)
{
  __shared__ __align__(16) unsigned char sWx[16384];
  __shared__ __align__(16) unsigned char sW2[16384];
  __shared__ __align__(16) unsigned char sT[4][2048];   // per-tile timeshared z^T/sp^T (2KB, fp8)

  const int tid = threadIdx.x;
  const int rowbase = blockIdx.x*64;

  // stage fp8 weights into LDS: plain linear copy
  for (int it=0; it<4; ++it){
    int L = it*4096 + tid*16;
    *(int4*)(sWx + L) = *(const int4*)(wxb + L);
    *(int4*)(sW2 + L) = *(const int4*)(w2b + L);
  }
  __syncthreads();

  const int w = tid>>6, tg = w>>1, hw = w&1, l = tid&63, q = l&15, g = l>>4;
  unsigned char* zB0 = &sT[2*tg][0];
  unsigned char* zB1 = &sT[2*tg+1][0];
  const unsigned char* wxBase = sWx + hw*8192 + l*8;   // + (j*4+kc)*512 imm
  const unsigned char* w2Base = sW2 + hw*8192 + l*8;
  const int hof = hw*64 + 4*g;                  // h/e base for this wave: + 16*j + r

  // loop-invariant LDS addresses (fp8 layout: linear, conflict-free)
  int wadr[4], radr[4];
  #pragma unroll
  for (int j=0; j<4; ++j) wadr[j] = (hw*4+j)*256 + q*8 + 4*(g&1) + 128*(g>>1);
  #pragma unroll
  for (int kc=0; kc<4; ++kc) radr[kc] = kc*512 + g*128 + q*8;

  const int row0 = rowbase + tg*32 + q;
  const int row1 = row0 + 16;
  const int sb0 = row0/TTOK, tt0 = row0 - sb0*TTOK;
  const int sb1 = row1/TTOK, tt1 = row1 - sb1*TTOK;

  h2 zbp0[4][2], zbp1[4][2];   // z state, packed f16 (16 VGPRs)
  h2 ksp0[4][2], ksp1[4][2];   // RK4 running sum, packed f16 (16 VGPRs)
  f32x4 wk0[4], wk1[4];        // f32 accumulators
  f32x4 b2r[4];                // persistent b2 (f32 seeds)
  h2 ccp[4][2];                // persistent c, packed f16
  h2 dlt20 = (h2){0,0}, dlt21 = (h2){0,0};

  #pragma unroll
  for (int j=0; j<4; ++j){
    f32x4 e0 = *(const f32x4*)(emb + tt0*128 + hof + 16*j);
    f32x4 e1 = *(const f32x4*)(emb + tt1*128 + hof + 16*j);
    zbp0[j][0] = pkh(e0[0], e0[1]);
    zbp0[j][1] = pkh(e0[2], e0[3]);
    zbp1[j][0] = pkh(e1[0], e1[1]);
    zbp1[j][1] = pkh(e1[2], e1[3]);
    wk0[j] = (f32x4){0.f,0.f,0.f,0.f};
    wk1[j] = (f32x4){0.f,0.f,0.f,0.f};
    ksp0[j][0] = (h2){0,0}; ksp0[j][1] = (h2){0,0};
    ksp1[j][0] = (h2){0,0}; ksp1[j][1] = (h2){0,0};
    b2r[j] = *(const f32x4*)(b2g + hof + 16*j);
    f32x4 c4 = *(const f32x4*)(cg + hof + 16*j);
    ccp[j][0] = pkh(c4[0], c4[1]);
    ccp[j][1] = pkh(c4[2], c4[3]);
  }

  #pragma unroll 1
  for (int se=0; se<8; ++se){
    const int   s    = se>>2, e = se&3;
    const float coef = (e==0)?0.f:((e==3)?0.5f:0.25f); // z_eval = z_base + coef*k_prev
    const float we   = (e==1||e==2)?2.f:1.f;
    const int   ti   = 2*s + ((e==0)?0:((e<3)?1:2));
    const _Float16 ch = (_Float16)coef;
    const h2 coef2 = {ch, ch};
    const _Float16 wh_ = (_Float16)we;
    const h2 we2 = {wh_, wh_};
    const h2 c12 = {(_Float16)(1.f/12.f), (_Float16)(1.f/12.f)};

    // ---- phase 1: prefetch hb seeds; z_eval (packed f16) -> fp8 -> z^T
    // (coef=0 at e==0 reproduces z exactly; wk init'd 0)
    f32x4 hb0[4], hb1[4];
    {
      const float* p0 = hbt + (ti*16 + sb0)*128 + hof;
      const float* p1 = hbt + (ti*16 + sb1)*128 + hof;
      #pragma unroll
      for (int j=0; j<4; ++j){
        hb0[j] = *(const f32x4*)(p0 + 16*j);
        hb1[j] = *(const f32x4*)(p1 + 16*j);
      }
    }
    #pragma unroll
    for (int j=0; j<4; ++j){
      h2 k00 = pkh(wk0[j][0], wk0[j][1]);
      h2 k01 = pkh(wk0[j][2], wk0[j][3]);
      h2 z00 = coef2*k00 + zbp0[j][0];
      h2 z01 = coef2*k01 + zbp0[j][1];
      *(int*)(zB0 + wadr[j]) = pk2fp8(z00, z01);
      h2 k10 = pkh(wk1[j][0], wk1[j][1]);
      h2 k11 = pkh(wk1[j][2], wk1[j][3]);
      h2 z10 = coef2*k10 + zbp1[j][0];
      h2 z11 = coef2*k11 + zbp1[j][1];
      *(int*)(zB1 + wadr[j]) = pk2fp8(z10, z11);
    }
    SBAR();
    __syncthreads();   // z^T complete (both halves, both tiles)

    // ---- phase 2: matmul1 (h-half, both tiles), fp8 MFMA: seed = prefetched hb
    #pragma unroll
    for (int j=0; j<4; ++j){ wk0[j] = hb0[j]; wk1[j] = hb1[j]; }
    __builtin_amdgcn_s_setprio(1);
    #pragma unroll
    for (int kc=0; kc<4; ++kc){
      long zf0 = *(const long*)(zB0 + radr[kc]);
      long zf1 = *(const long*)(zB1 + radr[kc]);
      #pragma unroll
      for (int j=0; j<4; ++j){
        long af = *(const long*)(wxBase + (j*4+kc)*512);
        wk0[j] = __builtin_amdgcn_mfma_f32_16x16x32_fp8_fp8(af, zf0, wk0[j], 0,0,0);
        wk1[j] = __builtin_amdgcn_mfma_f32_16x16x32_fp8_fp8(af, zf1, wk1[j], 0,0,0);
      }
      SBAR();
    }
    __builtin_amdgcn_s_setprio(0);
    __syncthreads();   // z^T reads done; buffers free for sp^T

    // ---- phase 3: packed-f16 softplus -> fp8 sp^T (direct h2->fp8), sigmoid*c -> div
    h2 dv20 = (h2){0,0}, dv21 = (h2){0,0};
    #pragma unroll
    for (int j=0; j<4; ++j){
      h2 p00 = pkh(wk0[j][0], wk0[j][1]);
      h2 p01 = pkh(wk0[j][2], wk0[j][3]);
      h2 s00 = spsig(p00, ccp[j][0], dv20);
      h2 s01 = spsig(p01, ccp[j][1], dv20);
      *(int*)(zB0 + wadr[j]) = pk2fp8(s00, s01);
      h2 p10 = pkh(wk1[j][0], wk1[j][1]);
      h2 p11 = pkh(wk1[j][2], wk1[j][3]);
      h2 s10 = spsig(p10, ccp[j][0], dv21);
      h2 s11 = spsig(p11, ccp[j][1], dv21);
      *(int*)(zB1 + wadr[j]) = pk2fp8(s10, s11);
    }
    dlt20 = we2*dv20 + dlt20;
    dlt21 = we2*dv21 + dlt21;
    SBAR();
    __syncthreads();   // sp^T complete

    // ---- phase 4: matmul2 (o-half, both tiles), fp8 MFMA: seed = persistent b2
    #pragma unroll
    for (int j=0; j<4; ++j){ wk0[j] = b2r[j]; wk1[j] = b2r[j]; }
    __builtin_amdgcn_s_setprio(1);
    #pragma unroll
    for (int kc=0; kc<4; ++kc){
      long sf0 = *(const long*)(zB0 + radr[kc]);
      long sf1 = *(const long*)(zB1 + radr[kc]);
      #pragma unroll
      for (int j=0; j<4; ++j){
        long af = *(const long*)(w2Base + (j*4+kc)*512);
        wk0[j] = __builtin_amdgcn_mfma_f32_16x16x32_fp8_fp8(af, sf0, wk0[j], 0,0,0);
        wk1[j] = __builtin_amdgcn_mfma_f32_16x16x32_fp8_fp8(af, sf1, wk1[j], 0,0,0);
      }
      SBAR();
    }
    __builtin_amdgcn_s_setprio(0);

    // ---- phase 5: RK4 accumulate (both tiles; wk = k_e), packed f16
    if (e==0){
      #pragma unroll
      for (int j=0;j<4;++j){
        ksp0[j][0] = pkh(wk0[j][0], wk0[j][1]);
        ksp0[j][1] = pkh(wk0[j][2], wk0[j][3]);
        ksp1[j][0] = pkh(wk1[j][0], wk1[j][1]);
        ksp1[j][1] = pkh(wk1[j][2], wk1[j][3]);
      }
    } else if (e<3){
      #pragma unroll
      for (int j=0;j<4;++j){
        ksp0[j][0] = we2*pkh(wk0[j][0], wk0[j][1]) + ksp0[j][0];
        ksp0[j][1] = we2*pkh(wk0[j][2], wk0[j][3]) + ksp0[j][1];
        ksp1[j][0] = we2*pkh(wk1[j][0], wk1[j][1]) + ksp1[j][0];
        ksp1[j][1] = we2*pkh(wk1[j][2], wk1[j][3]) + ksp1[j][1];
      }
    } else {
      #pragma unroll
      for (int j=0;j<4;++j){
        h2 t00 = ksp0[j][0] + pkh(wk0[j][0], wk0[j][1]);
        h2 t01 = ksp0[j][1] + pkh(wk0[j][2], wk0[j][3]);
        zbp0[j][0] = c12*t00 + zbp0[j][0];
        zbp0[j][1] = c12*t01 + zbp0[j][1];
        h2 t10 = ksp1[j][0] + pkh(wk1[j][0], wk1[j][1]);
        h2 t11 = ksp1[j][1] + pkh(wk1[j][2], wk1[j][3]);
        zbp1[j][0] = c12*t10 + zbp1[j][0];
        zbp1[j][1] = c12*t11 + zbp1[j][1];
      }
    }
    SBAR();
    __syncthreads();   // sp^T reads done; buffers free for next eval's z^T
  }

  // ---- epilogue: g-reduce div partials, cross-wave combine via LDS (reuse zB0)
  {
    float d0 = (float)dlt20[0] + (float)dlt20[1];
    float d1 = (float)dlt21[0] + (float)dlt21[1];
    d0 += __shfl_xor(d0, 16, 64);
    d0 += __shfl_xor(d0, 32, 64);
    d1 += __shfl_xor(d1, 16, 64);
    d1 += __shfl_xor(d1, 32, 64);
    float* fDv = (float*)zB0;
    if (g==0){
      fDv[hw*16 + q]      = d0;
      fDv[32 + hw*16 + q] = d1;
    }
    __syncthreads();
    if (hw==0 && g==0){
      float t0 = (fDv[q] + fDv[16+q]) * (1.f/12.f);
      float t1 = (fDv[32+q] + fDv[48+q]) * (1.f/12.f);
      out[row0] = lp0[row0] - t0;
      out[row1] = lp0[row1] - t1;
    }
  }
}

extern "C" void kernel_launch(void* const* d_in, const int* in_sizes, int n_in,
                              void* d_out, int out_size, void* d_ws, size_t ws_size,
                              hipStream_t stream) {
  const float* h    = (const float*)d_in[0];
  const float* emb  = (const float*)d_in[1];
  const float* lp0  = (const float*)d_in[2];
  const float* Wx   = (const float*)d_in[3];
  const float* wxt  = (const float*)d_in[4];
  const float* bx   = (const float*)d_in[5];
  const float* Wh   = (const float*)d_in[6];
  const float* wht  = (const float*)d_in[7];
  const float* bh   = (const float*)d_in[8];
  const float* W2   = (const float*)d_in[9];
  const float* b2   = (const float*)d_in[10];
  float* out = (float*)d_out;

  char* ws = (char*)d_ws;
  float* hbt          = (float*)ws;                    // 5*16*128 f32 = 40960 B
  float* cv           = (float*)(ws + 40960);          // 128 f32     = 512 B
  unsigned char* wxb  = (unsigned char*)(ws + 41472);  // 16384 fp8   = 16384 B
  unsigned char* w2b  = (unsigned char*)(ws + 57856);  // 16384 fp8   = 16384 B

  cnf_prep<<<19, 256, 0, stream>>>(h, Wx, wxt, bx, Wh, wht, bh, W2, hbt, cv, wxb, w2b);
  cnf_main<<<2500, 256, 0, stream>>>(emb, lp0, b2, hbt, cv, wxb, w2b, out);
}

// Round 25
// 130.380 us; speedup vs baseline: 5.0336x; 1.1044x over previous
//
#include <hip/hip_runtime.h>
#include <hip/hip_fp16.h>

typedef __attribute__((ext_vector_type(4))) float f32x4;
typedef _Float16 h2 __attribute__((ext_vector_type(2)));

#define TTOK 10000
#define SBAR() __builtin_amdgcn_sched_barrier(0)

__device__ __forceinline__ h2 pkh(float lo, float hi){
  auto t = __builtin_amdgcn_cvt_pkrtz(lo, hi);
  union{ decltype(t) a; h2 b; } c; c.a = t; return c.b;
}
__device__ __forceinline__ unsigned h2u(h2 v){ union{h2 h; unsigned u;} c; c.h=v; return c.u; }
__device__ __forceinline__ h2 u2h(unsigned u){ union{unsigned a; h2 b;} c; c.a=u; return c.b; }
__device__ __forceinline__ __half2 h2h(h2 v){ union{h2 a; __half2 b;} c; c.a=v; return c.b; }
__device__ __forceinline__ h2 hh2(__half2 v){ union{__half2 a; h2 b;} c; c.a=v; return c.b; }

__device__ __forceinline__ unsigned short f2h(float f){
  _Float16 h = (_Float16)f;
  union{_Float16 h; unsigned short u;} c; c.h = h; return c.u;
}

// gfx950 packed f16 -> fp8(e4m3) convert, scale = 1.0 (identity).
__device__ __forceinline__ int pk2fp8(h2 lo, h2 hi){
  int d = 0;
  asm("v_cvt_scalef32_pk_fp8_f16 %0, %1, 1.0" : "+v"(d) : "v"(lo));
  asm("v_cvt_scalef32_pk_fp8_f16 %0, %1, 1.0 op_sel:[0,0,1]" : "+v"(d) : "v"(hi));
  return d;
}

// Round-25 softplus+sigmoid: ONLY exp2 stays transcendental (2 scalar trans
// per h2); rcp and log replaced by packed-f16 polynomials.
//   u = e^{-|x|};  1/(1+u): quad init + 1 Newton (err ~5e-4)
//   ln(1+u) ~= u*(1 - 0.44943u + 0.14258u^2)  (err <= 2.5e-3; sp is fp8-bound)
__device__ __forceinline__ h2 spsig(h2 ph, h2 cc, h2& dv){
  const h2 nl2e = {(_Float16)(-1.4426950f), (_Float16)(-1.4426950f)};
  const h2 one  = {(_Float16)1.f, (_Float16)1.f};
  const h2 two  = {(_Float16)2.f, (_Float16)2.f};
  const h2 hlf  = {(_Float16)0.5f, (_Float16)0.5f};
  const h2 q2   = {(_Float16)0.355f, (_Float16)0.355f};
  const h2 q1   = {(_Float16)(-1.565f), (_Float16)(-1.565f)};
  const h2 q0   = {(_Float16)2.210f, (_Float16)2.210f};
  const h2 l2   = {(_Float16)0.14258f, (_Float16)0.14258f};
  const h2 l1   = {(_Float16)(-0.44943f), (_Float16)(-0.44943f)};
  unsigned pu = h2u(ph);
  h2 ax = u2h(pu & 0x7FFF7FFFu);                 // |x|
  h2 sn = u2h((pu & 0x80008000u) | 0x3C003C00u); // +-1
  h2 u  = hh2(h2exp2(h2h(ax*nl2e)));             // e^{-|x|}   (2 trans)
  h2 d  = u + one;
  h2 y  = (d*q2 + q1)*d + q0;                    // quad init of 1/d
  y     = y*(two - d*y);                         // Newton
  h2 Lp = u*((u*l2 + l1)*u + one);               // ln(1+u)
  h2 sp = (ph + ax)*hlf + Lp;                    // softplus
  h2 sg = sn*(y - hlf) + hlf;                    // sigmoid
  dv = sg*cc + dv;
  return sp;
}

// ---------------- prep: fragment-linear FP8 (e4m3) weights, hb seeds, c ----------------
__global__ void cnf_prep(const float* __restrict__ h, const float* __restrict__ Wx,
                         const float* __restrict__ wxt, const float* __restrict__ bx,
                         const float* __restrict__ Wh, const float* __restrict__ wht,
                         const float* __restrict__ bh, const float* __restrict__ W2,
                         float* __restrict__ hbt, float* __restrict__ cv,
                         unsigned char* __restrict__ wxb, unsigned char* __restrict__ w2b)
{
  const int b = blockIdx.x, t = threadIdx.x;
  if (b < 16) {
    const int jj = b & 7;
    const float* W = (b < 8) ? Wx : W2;
    unsigned char* dst = (b < 8) ? wxb : w2b;
    const int kc = t>>6, l = t&63, q = l&15, g = l>>4;
    #pragma unroll
    for (int i=0;i<8;++i){
      float wv = W[(jj*16+q)*128 + kc*32 + g*8 + i];
      unsigned pkv = __builtin_amdgcn_cvt_pk_fp8_f32(wv, wv, 0, false);
      dst[((jj*4+kc)*64 + l)*8 + i] = (unsigned char)(pkv & 0xFF);
    }
  } else if (b < 18) {
    for (int i=0;i<4;++i){
      int idx = i*256 + t;
      int sb = (b-16)*8 + (idx>>7);
      int j  = idx & 127;
      float a = 0.f;
      for (int e2=0;e2<128;++e2) a += h[sb*128+e2]*Wh[j*128+e2];
      float base = a + bh[j] + bx[j];
      float tw   = wxt[j] + wht[j];
      for (int ti=0; ti<5; ++ti)
        hbt[(ti*16+sb)*128 + j] = base + 0.25f*(float)ti*tw;   // t in {0,.25,.5,.75,1}
    }
  } else {
    if (t < 128){
      float a = 0.f;
      for (int i=0;i<128;++i) a += W2[i*128+t]*Wx[t*128+i];
      cv[t] = a;
    }
  }
}

// ---------------- fused CNF main kernel ----------------
// Round-25 = round-24 fp8 structure + (a) poly softplus/sigmoid (6->2 trans
// per h2 -- trans were the measured VALU wall), (b) kp registers reuse the
// phase-5 pkh(wk) results in the next eval's phase 1 (-16 pkh/eval).
__global__ __launch_bounds__(256, 3) void cnf_main(
    const float* __restrict__ emb, const float* __restrict__ lp0,
    const float* __restrict__ b2g, const float* __restrict__ hbt,
    const float* __restrict__ cg,  const unsigned char* __restrict__ wxb,
    const unsigned char* __restrict__ w2b, float* __restrict__ out)
{
  __shared__ __align__(16) unsigned char sWx[16384];
  __shared__ __align__(16) unsigned char sW2[16384];
  __shared__ __align__(16) unsigned char sT[4][2048];   // per-tile timeshared z^T/sp^T (2KB, fp8)

  const int tid = threadIdx.x;
  const int rowbase = blockIdx.x*64;

  // stage fp8 weights into LDS: plain linear copy
  for (int it=0; it<4; ++it){
    int L = it*4096 + tid*16;
    *(int4*)(sWx + L) = *(const int4*)(wxb + L);
    *(int4*)(sW2 + L) = *(const int4*)(w2b + L);
  }
  __syncthreads();

  const int w = tid>>6, tg = w>>1, hw = w&1, l = tid&63, q = l&15, g = l>>4;
  unsigned char* zB0 = &sT[2*tg][0];
  unsigned char* zB1 = &sT[2*tg+1][0];
  const unsigned char* wxBase = sWx + hw*8192 + l*8;   // + (j*4+kc)*512 imm
  const unsigned char* w2Base = sW2 + hw*8192 + l*8;
  const int hof = hw*64 + 4*g;                  // h/e base for this wave: + 16*j + r

  // loop-invariant LDS addresses (fp8 layout: linear, conflict-free)
  int wadr[4], radr[4];
  #pragma unroll
  for (int j=0; j<4; ++j) wadr[j] = (hw*4+j)*256 + q*8 + 4*(g&1) + 128*(g>>1);
  #pragma unroll
  for (int kc=0; kc<4; ++kc) radr[kc] = kc*512 + g*128 + q*8;

  const int row0 = rowbase + tg*32 + q;
  const int row1 = row0 + 16;
  const int sb0 = row0/TTOK, tt0 = row0 - sb0*TTOK;
  const int sb1 = row1/TTOK, tt1 = row1 - sb1*TTOK;

  h2 zbp0[4][2], zbp1[4][2];   // z state, packed f16 (16 VGPRs)
  h2 ksp0[4][2], ksp1[4][2];   // RK4 running sum, packed f16 (16 VGPRs)
  h2 kp0[4][2],  kp1[4][2];    // prev-eval k, packed f16 (phase5 -> phase1 reuse)
  f32x4 wk0[4], wk1[4];        // f32 accumulators
  f32x4 b2r[4];                // persistent b2 (f32 seeds)
  h2 ccp[4][2];                // persistent c, packed f16
  h2 dlt20 = (h2){0,0}, dlt21 = (h2){0,0};

  #pragma unroll
  for (int j=0; j<4; ++j){
    f32x4 e0 = *(const f32x4*)(emb + tt0*128 + hof + 16*j);
    f32x4 e1 = *(const f32x4*)(emb + tt1*128 + hof + 16*j);
    zbp0[j][0] = pkh(e0[0], e0[1]);
    zbp0[j][1] = pkh(e0[2], e0[3]);
    zbp1[j][0] = pkh(e1[0], e1[1]);
    zbp1[j][1] = pkh(e1[2], e1[3]);
    wk0[j] = (f32x4){0.f,0.f,0.f,0.f};
    wk1[j] = (f32x4){0.f,0.f,0.f,0.f};
    ksp0[j][0] = (h2){0,0}; ksp0[j][1] = (h2){0,0};
    ksp1[j][0] = (h2){0,0}; ksp1[j][1] = (h2){0,0};
    kp0[j][0] = (h2){0,0};  kp0[j][1] = (h2){0,0};
    kp1[j][0] = (h2){0,0};  kp1[j][1] = (h2){0,0};
    b2r[j] = *(const f32x4*)(b2g + hof + 16*j);
    f32x4 c4 = *(const f32x4*)(cg + hof + 16*j);
    ccp[j][0] = pkh(c4[0], c4[1]);
    ccp[j][1] = pkh(c4[2], c4[3]);
  }

  #pragma unroll 1
  for (int se=0; se<8; ++se){
    const int   s    = se>>2, e = se&3;
    const float coef = (e==0)?0.f:((e==3)?0.5f:0.25f); // z_eval = z_base + coef*k_prev
    const float we   = (e==1||e==2)?2.f:1.f;
    const int   ti   = 2*s + ((e==0)?0:((e<3)?1:2));
    const _Float16 ch = (_Float16)coef;
    const h2 coef2 = {ch, ch};
    const _Float16 wh_ = (_Float16)we;
    const h2 we2 = {wh_, wh_};
    const h2 c12 = {(_Float16)(1.f/12.f), (_Float16)(1.f/12.f)};

    // ---- phase 1: prefetch hb seeds; z_eval = coef*kp + z (packed f16) -> fp8 -> z^T
    // (kp holds pkh(k_prev) from phase 5; kp=0 at se==0 so coef path is exact)
    f32x4 hb0[4], hb1[4];
    {
      const float* p0 = hbt + (ti*16 + sb0)*128 + hof;
      const float* p1 = hbt + (ti*16 + sb1)*128 + hof;
      #pragma unroll
      for (int j=0; j<4; ++j){
        hb0[j] = *(const f32x4*)(p0 + 16*j);
        hb1[j] = *(const f32x4*)(p1 + 16*j);
      }
    }
    #pragma unroll
    for (int j=0; j<4; ++j){
      h2 z00 = coef2*kp0[j][0] + zbp0[j][0];
      h2 z01 = coef2*kp0[j][1] + zbp0[j][1];
      *(int*)(zB0 + wadr[j]) = pk2fp8(z00, z01);
      h2 z10 = coef2*kp1[j][0] + zbp1[j][0];
      h2 z11 = coef2*kp1[j][1] + zbp1[j][1];
      *(int*)(zB1 + wadr[j]) = pk2fp8(z10, z11);
    }
    SBAR();
    __syncthreads();   // z^T complete (both halves, both tiles)

    // ---- phase 2: matmul1 (h-half, both tiles), fp8 MFMA: seed = prefetched hb
    #pragma unroll
    for (int j=0; j<4; ++j){ wk0[j] = hb0[j]; wk1[j] = hb1[j]; }
    __builtin_amdgcn_s_setprio(1);
    #pragma unroll
    for (int kc=0; kc<4; ++kc){
      long zf0 = *(const long*)(zB0 + radr[kc]);
      long zf1 = *(const long*)(zB1 + radr[kc]);
      #pragma unroll
      for (int j=0; j<4; ++j){
        long af = *(const long*)(wxBase + (j*4+kc)*512);
        wk0[j] = __builtin_amdgcn_mfma_f32_16x16x32_fp8_fp8(af, zf0, wk0[j], 0,0,0);
        wk1[j] = __builtin_amdgcn_mfma_f32_16x16x32_fp8_fp8(af, zf1, wk1[j], 0,0,0);
      }
      SBAR();
    }
    __builtin_amdgcn_s_setprio(0);
    __syncthreads();   // z^T reads done; buffers free for sp^T

    // ---- phase 3: poly softplus -> fp8 sp^T, sigmoid*c -> div
    h2 dv20 = (h2){0,0}, dv21 = (h2){0,0};
    #pragma unroll
    for (int j=0; j<4; ++j){
      h2 p00 = pkh(wk0[j][0], wk0[j][1]);
      h2 p01 = pkh(wk0[j][2], wk0[j][3]);
      h2 s00 = spsig(p00, ccp[j][0], dv20);
      h2 s01 = spsig(p01, ccp[j][1], dv20);
      *(int*)(zB0 + wadr[j]) = pk2fp8(s00, s01);
      h2 p10 = pkh(wk1[j][0], wk1[j][1]);
      h2 p11 = pkh(wk1[j][2], wk1[j][3]);
      h2 s10 = spsig(p10, ccp[j][0], dv21);
      h2 s11 = spsig(p11, ccp[j][1], dv21);
      *(int*)(zB1 + wadr[j]) = pk2fp8(s10, s11);
    }
    dlt20 = we2*dv20 + dlt20;
    dlt21 = we2*dv21 + dlt21;
    SBAR();
    __syncthreads();   // sp^T complete

    // ---- phase 4: matmul2 (o-half, both tiles), fp8 MFMA: seed = persistent b2
    #pragma unroll
    for (int j=0; j<4; ++j){ wk0[j] = b2r[j]; wk1[j] = b2r[j]; }
    __builtin_amdgcn_s_setprio(1);
    #pragma unroll
    for (int kc=0; kc<4; ++kc){
      long sf0 = *(const long*)(zB0 + radr[kc]);
      long sf1 = *(const long*)(zB1 + radr[kc]);
      #pragma unroll
      for (int j=0; j<4; ++j){
        long af = *(const long*)(w2Base + (j*4+kc)*512);
        wk0[j] = __builtin_amdgcn_mfma_f32_16x16x32_fp8_fp8(af, sf0, wk0[j], 0,0,0);
        wk1[j] = __builtin_amdgcn_mfma_f32_16x16x32_fp8_fp8(af, sf1, wk1[j], 0,0,0);
      }
      SBAR();
    }
    __builtin_amdgcn_s_setprio(0);

    // ---- phase 5: RK4 accumulate (both tiles; wk = k_e); kp saved for next phase 1
    if (e<3){
      #pragma unroll
      for (int j=0;j<4;++j){
        kp0[j][0] = pkh(wk0[j][0], wk0[j][1]);
        kp0[j][1] = pkh(wk0[j][2], wk0[j][3]);
        kp1[j][0] = pkh(wk1[j][0], wk1[j][1]);
        kp1[j][1] = pkh(wk1[j][2], wk1[j][3]);
      }
      if (e==0){
        #pragma unroll
        for (int j=0;j<4;++j){
          ksp0[j][0] = kp0[j][0]; ksp0[j][1] = kp0[j][1];
          ksp1[j][0] = kp1[j][0]; ksp1[j][1] = kp1[j][1];
        }
      } else {
        #pragma unroll
        for (int j=0;j<4;++j){
          ksp0[j][0] = we2*kp0[j][0] + ksp0[j][0];
          ksp0[j][1] = we2*kp0[j][1] + ksp0[j][1];
          ksp1[j][0] = we2*kp1[j][0] + ksp1[j][0];
          ksp1[j][1] = we2*kp1[j][1] + ksp1[j][1];
        }
      }
    } else {
      #pragma unroll
      for (int j=0;j<4;++j){
        h2 t00 = ksp0[j][0] + pkh(wk0[j][0], wk0[j][1]);
        h2 t01 = ksp0[j][1] + pkh(wk0[j][2], wk0[j][3]);
        zbp0[j][0] = c12*t00 + zbp0[j][0];
        zbp0[j][1] = c12*t01 + zbp0[j][1];
        h2 t10 = ksp1[j][0] + pkh(wk1[j][0], wk1[j][1]);
        h2 t11 = ksp1[j][1] + pkh(wk1[j][2], wk1[j][3]);
        zbp1[j][0] = c12*t10 + zbp1[j][0];
        zbp1[j][1] = c12*t11 + zbp1[j][1];
        kp0[j][0] = (h2){0,0}; kp0[j][1] = (h2){0,0};   // next eval is e==0 (coef=0)
        kp1[j][0] = (h2){0,0}; kp1[j][1] = (h2){0,0};
      }
    }
    SBAR();
    __syncthreads();   // sp^T reads done; buffers free for next eval's z^T
  }

  // ---- epilogue: g-reduce div partials, cross-wave combine via LDS (reuse zB0)
  {
    float d0 = (float)dlt20[0] + (float)dlt20[1];
    float d1 = (float)dlt21[0] + (float)dlt21[1];
    d0 += __shfl_xor(d0, 16, 64);
    d0 += __shfl_xor(d0, 32, 64);
    d1 += __shfl_xor(d1, 16, 64);
    d1 += __shfl_xor(d1, 32, 64);
    float* fDv = (float*)zB0;
    if (g==0){
      fDv[hw*16 + q]      = d0;
      fDv[32 + hw*16 + q] = d1;
    }
    __syncthreads();
    if (hw==0 && g==0){
      float t0 = (fDv[q] + fDv[16+q]) * (1.f/12.f);
      float t1 = (fDv[32+q] + fDv[48+q]) * (1.f/12.f);
      out[row0] = lp0[row0] - t0;
      out[row1] = lp0[row1] - t1;
    }
  }
}

extern "C" void kernel_launch(void* const* d_in, const int* in_sizes, int n_in,
                              void* d_out, int out_size, void* d_ws, size_t ws_size,
                              hipStream_t stream) {
  const float* h    = (const float*)d_in[0];
  const float* emb  = (const float*)d_in[1];
  const float* lp0  = (const float*)d_in[2];
  const float* Wx   = (const float*)d_in[3];
  const float* wxt  = (const float*)d_in[4];
  const float* bx   = (const float*)d_in[5];
  const float* Wh   = (const float*)d_in[6];
  const float* wht  = (const float*)d_in[7];
  const float* bh   = (const float*)d_in[8];
  const float* W2   = (const float*)d_in[9];
  const float* b2   = (const float*)d_in[10];
  float* out = (float*)d_out;

  char* ws = (char*)d_ws;
  float* hbt          = (float*)ws;                    // 5*16*128 f32 = 40960 B
  float* cv           = (float*)(ws + 40960);          // 128 f32     = 512 B
  unsigned char* wxb  = (unsigned char*)(ws + 41472);  // 16384 fp8   = 16384 B
  unsigned char* w2b  = (unsigned char*)(ws + 57856);  // 16384 fp8   = 16384 B

  cnf_prep<<<19, 256, 0, stream>>>(h, Wx, wxt, bx, Wh, wht, bh, W2, hbt, cv, wxb, w2b);
  cnf_main<<<2500, 256, 0, stream>>>(emb, lp0, b2, hbt, cv, wxb, w2b, out);
}

// Round 26
// 129.157 us; speedup vs baseline: 5.0813x; 1.0095x over previous
//
#include <hip/hip_runtime.h>
#include <hip/hip_fp16.h>

typedef __attribute__((ext_vector_type(4))) float f32x4;
typedef _Float16 h2 __attribute__((ext_vector_type(2)));

#define TTOK 10000
#define SBAR() __builtin_amdgcn_sched_barrier(0)

__device__ __forceinline__ h2 pkh(float lo, float hi){
  auto t = __builtin_amdgcn_cvt_pkrtz(lo, hi);
  union{ decltype(t) a; h2 b; } c; c.a = t; return c.b;
}
__device__ __forceinline__ unsigned h2u(h2 v){ union{h2 h; unsigned u;} c; c.h=v; return c.u; }
__device__ __forceinline__ h2 u2h(unsigned u){ union{unsigned a; h2 b;} c; c.a=u; return c.b; }
__device__ __forceinline__ __half2 h2h(h2 v){ union{h2 a; __half2 b;} c; c.a=v; return c.b; }
__device__ __forceinline__ h2 hh2(__half2 v){ union{__half2 a; h2 b;} c; c.a=v; return c.b; }

__device__ __forceinline__ unsigned short f2h(float f){
  _Float16 h = (_Float16)f;
  union{_Float16 h; unsigned short u;} c; c.h = h; return c.u;
}

// gfx950 packed f16 -> fp8(e4m3) convert, scale = 1.0 (identity).
__device__ __forceinline__ int pk2fp8(h2 lo, h2 hi){
  int d = 0;
  asm("v_cvt_scalef32_pk_fp8_f16 %0, %1, 1.0" : "+v"(d) : "v"(lo));
  asm("v_cvt_scalef32_pk_fp8_f16 %0, %1, 1.0 op_sel:[0,0,1]" : "+v"(d) : "v"(hi));
  return d;
}

// poly softplus+sigmoid (round 25, verified): only exp2 transcendental.
__device__ __forceinline__ h2 spsig(h2 ph, h2 cc, h2& dv){
  const h2 nl2e = {(_Float16)(-1.4426950f), (_Float16)(-1.4426950f)};
  const h2 one  = {(_Float16)1.f, (_Float16)1.f};
  const h2 two  = {(_Float16)2.f, (_Float16)2.f};
  const h2 hlf  = {(_Float16)0.5f, (_Float16)0.5f};
  const h2 q2   = {(_Float16)0.355f, (_Float16)0.355f};
  const h2 q1   = {(_Float16)(-1.565f), (_Float16)(-1.565f)};
  const h2 q0   = {(_Float16)2.210f, (_Float16)2.210f};
  const h2 l2   = {(_Float16)0.14258f, (_Float16)0.14258f};
  const h2 l1   = {(_Float16)(-0.44943f), (_Float16)(-0.44943f)};
  unsigned pu = h2u(ph);
  h2 ax = u2h(pu & 0x7FFF7FFFu);                 // |x|
  h2 sn = u2h((pu & 0x80008000u) | 0x3C003C00u); // +-1
  h2 u  = hh2(h2exp2(h2h(ax*nl2e)));             // e^{-|x|}   (2 trans)
  h2 d  = u + one;
  h2 y  = (d*q2 + q1)*d + q0;                    // quad init of 1/d
  y     = y*(two - d*y);                         // Newton
  h2 Lp = u*((u*l2 + l1)*u + one);               // ln(1+u)
  h2 sp = (ph + ax)*hlf + Lp;                    // softplus
  h2 sg = sn*(y - hlf) + hlf;                    // sigmoid
  dv = sg*cc + dv;
  return sp;
}

// ---------------- prep: fragment-linear FP8 (e4m3) weights, hb seeds, c ----------------
__global__ void cnf_prep(const float* __restrict__ h, const float* __restrict__ Wx,
                         const float* __restrict__ wxt, const float* __restrict__ bx,
                         const float* __restrict__ Wh, const float* __restrict__ wht,
                         const float* __restrict__ bh, const float* __restrict__ W2,
                         float* __restrict__ hbt, float* __restrict__ cv,
                         unsigned char* __restrict__ wxb, unsigned char* __restrict__ w2b)
{
  const int b = blockIdx.x, t = threadIdx.x;
  if (b < 16) {
    const int jj = b & 7;
    const float* W = (b < 8) ? Wx : W2;
    unsigned char* dst = (b < 8) ? wxb : w2b;
    const int kc = t>>6, l = t&63, q = l&15, g = l>>4;
    #pragma unroll
    for (int i=0;i<8;++i){
      float wv = W[(jj*16+q)*128 + kc*32 + g*8 + i];
      unsigned pkv = __builtin_amdgcn_cvt_pk_fp8_f32(wv, wv, 0, false);
      dst[((jj*4+kc)*64 + l)*8 + i] = (unsigned char)(pkv & 0xFF);
    }
  } else if (b < 18) {
    for (int i=0;i<4;++i){
      int idx = i*256 + t;
      int sb = (b-16)*8 + (idx>>7);
      int j  = idx & 127;
      float a = 0.f;
      for (int e2=0;e2<128;++e2) a += h[sb*128+e2]*Wh[j*128+e2];
      float base = a + bh[j] + bx[j];
      float tw   = wxt[j] + wht[j];
      for (int ti=0; ti<5; ++ti)
        hbt[(ti*16+sb)*128 + j] = base + 0.25f*(float)ti*tw;   // t in {0,.25,.5,.75,1}
    }
  } else {
    if (t < 128){
      float a = 0.f;
      for (int i=0;i<128;++i) a += W2[i*128+t]*Wx[t*128+i];
      cv[t] = a;
    }
  }
}

// ---------------- fused CNF main kernel ----------------
// Round-26 = round-25 + separate z^T / sp^T buffers -> 2 barriers/eval
// instead of 4. Hazards: B1 (z ready) orders z-write->mm1-read; B2 (sp
// ready) orders sp-write->mm2-read AND protects z^T for next eval's write
// (all waves past their mm1 reads); next B1 protects sp^T. LDS = 32KB
// weights + 16KB bufs = 48KB -> 3 blocks/CU (147KB < 160KB, clear of the
// r11 exact-fit trap). nt=2 fragment reuse intact (r18 lesson).
__global__ __launch_bounds__(256, 3) void cnf_main(
    const float* __restrict__ emb, const float* __restrict__ lp0,
    const float* __restrict__ b2g, const float* __restrict__ hbt,
    const float* __restrict__ cg,  const unsigned char* __restrict__ wxb,
    const unsigned char* __restrict__ w2b, float* __restrict__ out)
{
  __shared__ __align__(16) unsigned char sWx[16384];
  __shared__ __align__(16) unsigned char sW2[16384];
  __shared__ __align__(16) unsigned char sZ[4][2048];   // per-tile z^T (2KB, fp8)
  __shared__ __align__(16) unsigned char sP[4][2048];   // per-tile sp^T (2KB, fp8)

  const int tid = threadIdx.x;
  const int rowbase = blockIdx.x*64;

  // stage fp8 weights into LDS: plain linear copy
  for (int it=0; it<4; ++it){
    int L = it*4096 + tid*16;
    *(int4*)(sWx + L) = *(const int4*)(wxb + L);
    *(int4*)(sW2 + L) = *(const int4*)(w2b + L);
  }
  __syncthreads();

  const int w = tid>>6, tg = w>>1, hw = w&1, l = tid&63, q = l&15, g = l>>4;
  unsigned char* zB0 = &sZ[2*tg][0];
  unsigned char* zB1 = &sZ[2*tg+1][0];
  unsigned char* pB0 = &sP[2*tg][0];
  unsigned char* pB1 = &sP[2*tg+1][0];
  const unsigned char* wxBase = sWx + hw*8192 + l*8;   // + (j*4+kc)*512 imm
  const unsigned char* w2Base = sW2 + hw*8192 + l*8;
  const int hof = hw*64 + 4*g;                  // h/e base for this wave: + 16*j + r

  // loop-invariant LDS addresses (fp8 layout: linear, conflict-free)
  int wadr[4], radr[4];
  #pragma unroll
  for (int j=0; j<4; ++j) wadr[j] = (hw*4+j)*256 + q*8 + 4*(g&1) + 128*(g>>1);
  #pragma unroll
  for (int kc=0; kc<4; ++kc) radr[kc] = kc*512 + g*128 + q*8;

  const int row0 = rowbase + tg*32 + q;
  const int row1 = row0 + 16;
  const int sb0 = row0/TTOK, tt0 = row0 - sb0*TTOK;
  const int sb1 = row1/TTOK, tt1 = row1 - sb1*TTOK;

  h2 zbp0[4][2], zbp1[4][2];   // z state, packed f16 (16 VGPRs)
  h2 ksp0[4][2], ksp1[4][2];   // RK4 running sum, packed f16 (16 VGPRs)
  h2 kp0[4][2],  kp1[4][2];    // prev-eval k, packed f16 (phase5 -> phase1 reuse)
  f32x4 wk0[4], wk1[4];        // f32 accumulators
  f32x4 b2r[4];                // persistent b2 (f32 seeds)
  h2 ccp[4][2];                // persistent c, packed f16
  h2 dlt20 = (h2){0,0}, dlt21 = (h2){0,0};

  #pragma unroll
  for (int j=0; j<4; ++j){
    f32x4 e0 = *(const f32x4*)(emb + tt0*128 + hof + 16*j);
    f32x4 e1 = *(const f32x4*)(emb + tt1*128 + hof + 16*j);
    zbp0[j][0] = pkh(e0[0], e0[1]);
    zbp0[j][1] = pkh(e0[2], e0[3]);
    zbp1[j][0] = pkh(e1[0], e1[1]);
    zbp1[j][1] = pkh(e1[2], e1[3]);
    wk0[j] = (f32x4){0.f,0.f,0.f,0.f};
    wk1[j] = (f32x4){0.f,0.f,0.f,0.f};
    ksp0[j][0] = (h2){0,0}; ksp0[j][1] = (h2){0,0};
    ksp1[j][0] = (h2){0,0}; ksp1[j][1] = (h2){0,0};
    kp0[j][0] = (h2){0,0};  kp0[j][1] = (h2){0,0};
    kp1[j][0] = (h2){0,0};  kp1[j][1] = (h2){0,0};
    b2r[j] = *(const f32x4*)(b2g + hof + 16*j);
    f32x4 c4 = *(const f32x4*)(cg + hof + 16*j);
    ccp[j][0] = pkh(c4[0], c4[1]);
    ccp[j][1] = pkh(c4[2], c4[3]);
  }

  #pragma unroll 1
  for (int se=0; se<8; ++se){
    const int   s    = se>>2, e = se&3;
    const float coef = (e==0)?0.f:((e==3)?0.5f:0.25f); // z_eval = z_base + coef*k_prev
    const float we   = (e==1||e==2)?2.f:1.f;
    const int   ti   = 2*s + ((e==0)?0:((e<3)?1:2));
    const _Float16 ch = (_Float16)coef;
    const h2 coef2 = {ch, ch};
    const _Float16 wh_ = (_Float16)we;
    const h2 we2 = {wh_, wh_};
    const h2 c12 = {(_Float16)(1.f/12.f), (_Float16)(1.f/12.f)};

    // ---- phase 1: prefetch hb seeds; z_eval = coef*kp + z (packed f16) -> fp8 -> z^T
    f32x4 hb0[4], hb1[4];
    {
      const float* p0 = hbt + (ti*16 + sb0)*128 + hof;
      const float* p1 = hbt + (ti*16 + sb1)*128 + hof;
      #pragma unroll
      for (int j=0; j<4; ++j){
        hb0[j] = *(const f32x4*)(p0 + 16*j);
        hb1[j] = *(const f32x4*)(p1 + 16*j);
      }
    }
    #pragma unroll
    for (int j=0; j<4; ++j){
      h2 z00 = coef2*kp0[j][0] + zbp0[j][0];
      h2 z01 = coef2*kp0[j][1] + zbp0[j][1];
      *(int*)(zB0 + wadr[j]) = pk2fp8(z00, z01);
      h2 z10 = coef2*kp1[j][0] + zbp1[j][0];
      h2 z11 = coef2*kp1[j][1] + zbp1[j][1];
      *(int*)(zB1 + wadr[j]) = pk2fp8(z10, z11);
    }
    SBAR();
    __syncthreads();   // B1: z^T ready (also frees sp^T from prev eval's reads)

    // ---- phase 2: matmul1 (h-half, both tiles), fp8 MFMA: seed = prefetched hb
    #pragma unroll
    for (int j=0; j<4; ++j){ wk0[j] = hb0[j]; wk1[j] = hb1[j]; }
    __builtin_amdgcn_s_setprio(1);
    #pragma unroll
    for (int kc=0; kc<4; ++kc){
      long zf0 = *(const long*)(zB0 + radr[kc]);
      long zf1 = *(const long*)(zB1 + radr[kc]);
      #pragma unroll
      for (int j=0; j<4; ++j){
        long af = *(const long*)(wxBase + (j*4+kc)*512);
        wk0[j] = __builtin_amdgcn_mfma_f32_16x16x32_fp8_fp8(af, zf0, wk0[j], 0,0,0);
        wk1[j] = __builtin_amdgcn_mfma_f32_16x16x32_fp8_fp8(af, zf1, wk1[j], 0,0,0);
      }
      SBAR();
    }
    __builtin_amdgcn_s_setprio(0);

    // ---- phase 3: poly softplus -> fp8 sp^T, sigmoid*c -> div
    h2 dv20 = (h2){0,0}, dv21 = (h2){0,0};
    #pragma unroll
    for (int j=0; j<4; ++j){
      h2 p00 = pkh(wk0[j][0], wk0[j][1]);
      h2 p01 = pkh(wk0[j][2], wk0[j][3]);
      h2 s00 = spsig(p00, ccp[j][0], dv20);
      h2 s01 = spsig(p01, ccp[j][1], dv20);
      *(int*)(pB0 + wadr[j]) = pk2fp8(s00, s01);
      h2 p10 = pkh(wk1[j][0], wk1[j][1]);
      h2 p11 = pkh(wk1[j][2], wk1[j][3]);
      h2 s10 = spsig(p10, ccp[j][0], dv21);
      h2 s11 = spsig(p11, ccp[j][1], dv21);
      *(int*)(pB1 + wadr[j]) = pk2fp8(s10, s11);
    }
    dlt20 = we2*dv20 + dlt20;
    dlt21 = we2*dv21 + dlt21;
    SBAR();
    __syncthreads();   // B2: sp^T ready (also frees z^T for next eval's write)

    // ---- phase 4: matmul2 (o-half, both tiles), fp8 MFMA: seed = persistent b2
    #pragma unroll
    for (int j=0; j<4; ++j){ wk0[j] = b2r[j]; wk1[j] = b2r[j]; }
    __builtin_amdgcn_s_setprio(1);
    #pragma unroll
    for (int kc=0; kc<4; ++kc){
      long sf0 = *(const long*)(pB0 + radr[kc]);
      long sf1 = *(const long*)(pB1 + radr[kc]);
      #pragma unroll
      for (int j=0; j<4; ++j){
        long af = *(const long*)(w2Base + (j*4+kc)*512);
        wk0[j] = __builtin_amdgcn_mfma_f32_16x16x32_fp8_fp8(af, sf0, wk0[j], 0,0,0);
        wk1[j] = __builtin_amdgcn_mfma_f32_16x16x32_fp8_fp8(af, sf1, wk1[j], 0,0,0);
      }
      SBAR();
    }
    __builtin_amdgcn_s_setprio(0);

    // ---- phase 5: RK4 accumulate (both tiles; wk = k_e); kp saved for next phase 1
    if (e<3){
      #pragma unroll
      for (int j=0;j<4;++j){
        kp0[j][0] = pkh(wk0[j][0], wk0[j][1]);
        kp0[j][1] = pkh(wk0[j][2], wk0[j][3]);
        kp1[j][0] = pkh(wk1[j][0], wk1[j][1]);
        kp1[j][1] = pkh(wk1[j][2], wk1[j][3]);
      }
      if (e==0){
        #pragma unroll
        for (int j=0;j<4;++j){
          ksp0[j][0] = kp0[j][0]; ksp0[j][1] = kp0[j][1];
          ksp1[j][0] = kp1[j][0]; ksp1[j][1] = kp1[j][1];
        }
      } else {
        #pragma unroll
        for (int j=0;j<4;++j){
          ksp0[j][0] = we2*kp0[j][0] + ksp0[j][0];
          ksp0[j][1] = we2*kp0[j][1] + ksp0[j][1];
          ksp1[j][0] = we2*kp1[j][0] + ksp1[j][0];
          ksp1[j][1] = we2*kp1[j][1] + ksp1[j][1];
        }
      }
    } else {
      #pragma unroll
      for (int j=0;j<4;++j){
        h2 t00 = ksp0[j][0] + pkh(wk0[j][0], wk0[j][1]);
        h2 t01 = ksp0[j][1] + pkh(wk0[j][2], wk0[j][3]);
        zbp0[j][0] = c12*t00 + zbp0[j][0];
        zbp0[j][1] = c12*t01 + zbp0[j][1];
        h2 t10 = ksp1[j][0] + pkh(wk1[j][0], wk1[j][1]);
        h2 t11 = ksp1[j][1] + pkh(wk1[j][2], wk1[j][3]);
        zbp1[j][0] = c12*t10 + zbp1[j][0];
        zbp1[j][1] = c12*t11 + zbp1[j][1];
        kp0[j][0] = (h2){0,0}; kp0[j][1] = (h2){0,0};   // next eval is e==0 (coef=0)
        kp1[j][0] = (h2){0,0}; kp1[j][1] = (h2){0,0};
      }
    }
    SBAR();
  }

  // ---- epilogue: g-reduce div partials, cross-wave combine via LDS (reuse zB0)
  {
    float d0 = (float)dlt20[0] + (float)dlt20[1];
    float d1 = (float)dlt21[0] + (float)dlt21[1];
    d0 += __shfl_xor(d0, 16, 64);
    d0 += __shfl_xor(d0, 32, 64);
    d1 += __shfl_xor(d1, 16, 64);
    d1 += __shfl_xor(d1, 32, 64);
    __syncthreads();   // all mm2/p5 done; z^T buffers free
    float* fDv = (float*)zB0;
    if (g==0){
      fDv[hw*16 + q]      = d0;
      fDv[32 + hw*16 + q] = d1;
    }
    __syncthreads();
    if (hw==0 && g==0){
      float t0 = (fDv[q] + fDv[16+q]) * (1.f/12.f);
      float t1 = (fDv[32+q] + fDv[48+q]) * (1.f/12.f);
      out[row0] = lp0[row0] - t0;
      out[row1] = lp0[row1] - t1;
    }
  }
}

extern "C" void kernel_launch(void* const* d_in, const int* in_sizes, int n_in,
                              void* d_out, int out_size, void* d_ws, size_t ws_size,
                              hipStream_t stream) {
  const float* h    = (const float*)d_in[0];
  const float* emb  = (const float*)d_in[1];
  const float* lp0  = (const float*)d_in[2];
  const float* Wx   = (const float*)d_in[3];
  const float* wxt  = (const float*)d_in[4];
  const float* bx   = (const float*)d_in[5];
  const float* Wh   = (const float*)d_in[6];
  const float* wht  = (const float*)d_in[7];
  const float* bh   = (const float*)d_in[8];
  const float* W2   = (const float*)d_in[9];
  const float* b2   = (const float*)d_in[10];
  float* out = (float*)d_out;

  char* ws = (char*)d_ws;
  float* hbt          = (float*)ws;                    // 5*16*128 f32 = 40960 B
  float* cv           = (float*)(ws + 40960);          // 128 f32     = 512 B
  unsigned char* wxb  = (unsigned char*)(ws + 41472);  // 16384 fp8   = 16384 B
  unsigned char* w2b  = (unsigned char*)(ws + 57856);  // 16384 fp8   = 16384 B

  cnf_prep<<<19, 256, 0, stream>>>(h, Wx, wxt, bx, Wh, wht, bh, W2, hbt, cv, wxb, w2b);
  cnf_main<<<2500, 256, 0, stream>>>(emb, lp0, b2, hbt, cv, wxb, w2b, out);
}